// Round 4
// baseline (458.943 us; speedup 1.0000x reference)
//
#include <hip/hip_runtime.h>

// ---------------------------------------------------------------------------
// AttentionCritic on MI355X — round 4: double-buffered LDS + counted vmcnt
// (raw s_barrier, T4) + setprio (T5) on the bf16 MFMA GEMMs.
// N=8 agents, B=8192, S=64, A=16, H=512, E=4 heads, D=128.
// ---------------------------------------------------------------------------

#define DEVI __device__ __forceinline__

typedef unsigned short us16;
typedef __bf16 bf16x8 __attribute__((ext_vector_type(8)));
typedef float f32x4 __attribute__((ext_vector_type(4)));
typedef unsigned short u16x8 __attribute__((ext_vector_type(8)));

DEVI us16 f2bf(float f) {
  unsigned u = __builtin_bit_cast(unsigned, f);
  u += 0x7FFFu + ((u >> 16) & 1u);          // round-to-nearest-even
  return (us16)(u >> 16);
}
DEVI float bf2f(us16 h) {
  unsigned u = ((unsigned)h) << 16;
  return __builtin_bit_cast(float, u);
}
DEVI float lrelu(float v) { return v > 0.f ? v : 0.01f * v; }
DEVI int pk2(float a, float b) { return (int)f2bf(a) | ((int)f2bf(b) << 16); }

// async global->LDS, 16B per lane. LDS dest must be linear: base + lane*16.
DEVI void gload16(const us16* g, us16* l) {
  __builtin_amdgcn_global_load_lds(
      (const __attribute__((address_space(1))) void*)g,
      (__attribute__((address_space(3))) void*)l, 16, 0, 0);
}

// ---------------------------------------------------------------------------
// Transpose + fp32->bf16 convert:  dst[s][dstRowOff+o][k] = src[s][k][o] (k<K else 0)
// block (32,8), grid (Kpad/32, ceil(O/32), slices)
// ---------------------------------------------------------------------------
__global__ void tconv_k(const float* __restrict__ src, long srcSlice, int K, int O,
                        us16* __restrict__ dst, long dstSlice, int dstRowOff,
                        int ldd, int Kpad)
{
  __shared__ float t[32][33];
  const int s = blockIdx.z;
  const int k0 = blockIdx.x * 32, o0 = blockIdx.y * 32;
  const int lx = threadIdx.x, ly = threadIdx.y;
#pragma unroll
  for (int i = 0; i < 4; i++) {
    int k = k0 + ly + i * 8, o = o0 + lx;
    float v = 0.f;
    if (k < K && o < O) v = src[(long)s * srcSlice + (long)k * O + o];
    t[ly + i * 8][lx] = v;
  }
  __syncthreads();
#pragma unroll
  for (int i = 0; i < 4; i++) {
    int o = o0 + ly + i * 8, k = k0 + lx;
    if (o < O && k < Kpad)
      dst[(long)s * dstSlice + (long)(dstRowOff + o) * ldd + k] = f2bf(t[lx][ly + i * 8]);
  }
}

// ---------------------------------------------------------------------------
// fp32-input encoder GEMM (round-2 structure, BK=32, linear LDS).
// C[8192 x 512] = A[8192 x K] * Bt[512 x K]^T, bias + lrelu, bf16 store.
// ---------------------------------------------------------------------------
enum { ASRC_F32 = 2, ASRC_F32_CAT = 3 };

template <int ASRC, int KTOT>
__global__ __launch_bounds__(256, 4)
void enc_gemm_k(const float* __restrict__ Ap, long aSlice,
                const float* __restrict__ A2p, long a2Slice,
                const us16* __restrict__ Btp, long bSlice,
                const float* __restrict__ bias, long biasSlice,
                us16* __restrict__ outB, long outSlice, long outRow)
{
  __shared__ us16 lA[128 * 32];   // linear — required by global_load_lds
  __shared__ us16 lB[128 * 32];
  const int tid = threadIdx.x;
  const int z = blockIdx.z;
  const int m0 = blockIdx.x * 128;
  const int n0 = blockIdx.y * 128;
  const int wv = tid >> 6, lane = tid & 63;
  const int wm = (wv >> 1) * 64, wn = (wv & 1) * 64;
  const int fr = lane & 15, fk = (lane >> 4) * 8;
  const int rbase = (lane >> 4) * 4;
  const int grow = tid >> 2, gcol = (tid & 3) * 8;

  f32x4 acc[4][4];
#pragma unroll
  for (int i = 0; i < 4; i++)
#pragma unroll
    for (int j = 0; j < 4; j++) acc[i][j] = f32x4{0.f, 0.f, 0.f, 0.f};

  const us16* bbase = Btp + (long)z * bSlice + (long)n0 * KTOT;

  for (int k0 = 0; k0 < KTOT; k0 += 32) {
    int4 ra0, ra1;
    {
      const int srow = tid >> 1, scol0 = (tid & 1) * 16;
      const int kg = k0 + scol0;
      const float* a = nullptr;
      if constexpr (ASRC == ASRC_F32) {
        a = Ap + (long)z * aSlice + (long)(m0 + srow) * 64 + kg;
      } else {  // states(0..63) | actions(64..79) | zero pad(80..95)
        if (kg < 64)      a = Ap + (long)z * aSlice + (long)(m0 + srow) * 64 + kg;
        else if (kg < 80) a = A2p + (long)z * a2Slice + (long)(m0 + srow) * 16 + (kg - 64);
      }
      float4 f0, f1, f2, f3;
      if (a) { const float4* ap = (const float4*)a; f0 = ap[0]; f1 = ap[1]; f2 = ap[2]; f3 = ap[3]; }
      else   { f0 = make_float4(0.f, 0.f, 0.f, 0.f); f1 = f0; f2 = f0; f3 = f0; }
      ra0.x = pk2(f0.x, f0.y); ra0.y = pk2(f0.z, f0.w); ra0.z = pk2(f1.x, f1.y); ra0.w = pk2(f1.z, f1.w);
      ra1.x = pk2(f2.x, f2.y); ra1.y = pk2(f2.z, f2.w); ra1.z = pk2(f3.x, f3.y); ra1.w = pk2(f3.z, f3.w);
    }

    __syncthreads();
    {
      const us16* bb = bbase + k0 + gcol;
      gload16(bb + (long)grow * KTOT, &lB[tid * 8]);
      gload16(bb + (long)(64 + grow) * KTOT, &lB[2048 + tid * 8]);
    }
    {
      const int srow = tid >> 1, scol0 = (tid & 1) * 16;
      *(int4*)&lA[srow * 32 + scol0]     = ra0;
      *(int4*)&lA[srow * 32 + scol0 + 8] = ra1;
    }
    __syncthreads();

    bf16x8 af[4], bfg[4];
#pragma unroll
    for (int f = 0; f < 4; f++) af[f]  = *(const bf16x8*)&lA[(wm + f * 16 + fr) * 32 + fk];
#pragma unroll
    for (int f = 0; f < 4; f++) bfg[f] = *(const bf16x8*)&lB[(wn + f * 16 + fr) * 32 + fk];
#pragma unroll
    for (int fm = 0; fm < 4; fm++)
#pragma unroll
      for (int fn = 0; fn < 4; fn++)
        acc[fm][fn] = __builtin_amdgcn_mfma_f32_16x16x32_bf16(af[fm], bfg[fn], acc[fm][fn], 0, 0, 0);
  }

#pragma unroll
  for (int fm = 0; fm < 4; fm++) {
#pragma unroll
    for (int fn = 0; fn < 4; fn++) {
      int col = n0 + wn + fn * 16 + fr;
      float badd = bias[(long)z * biasSlice + col];
      us16* op = outB + (long)z * outSlice + (long)(m0 + wm + fm * 16 + rbase) * outRow + col;
#pragma unroll
      for (int j = 0; j < 4; j++) {
        float v = lrelu(acc[fm][fn][j] + badd);
        op[(long)j * outRow] = f2bf(v);
      }
    }
  }
}

// ---------------------------------------------------------------------------
// bf16 MFMA GEMM, BK=64, XOR-swizzled LDS, DOUBLE-BUFFERED with counted vmcnt:
//   per iter t: issue 8 gloads for tile t+1 into buf d^1, s_waitcnt vmcnt(8)
//   (tile t landed, t+1 still in flight), raw s_barrier, ds_read+32 MFMA from
//   buf d, raw s_barrier. Loads are never drained to 0 in the main loop.
// 128x128 tile, 4 waves, 64 KB LDS, 2 blocks/CU.
// CAT: A = [Ap row-512 | A2p row-512] concatenated along K (KTOT=1024).
// ---------------------------------------------------------------------------
enum { EPI_KSV = 1, EPI_DOT = 2 };

template <bool CAT, int KTOT>
DEVI void stage_tile(const us16* __restrict__ Ap, long aSlice,
                     const us16* __restrict__ A2p, long a2Slice,
                     const us16* __restrict__ bbase, int z, int m0, int k0,
                     int tid, us16* ldsA, us16* ldsB)
{
#pragma unroll
  for (int i = 0; i < 4; i++) {
    const int c = i * 256 + tid;               // 16B chunk index, 0..1023
    const int r = c >> 3;                      // tile row 0..127
    const int col = ((c & 7) ^ (r & 7)) << 3;  // inverse-swizzled source col
    const us16* a;
    if constexpr (!CAT) {
      a = Ap + (long)z * aSlice + (long)(m0 + r) * KTOT + (k0 + col);
    } else {
      const int kg = k0 + col;                 // 8-elem chunks never straddle 512
      a = (kg < 512) ? Ap  + (long)z * aSlice  + (long)(m0 + r) * 512 + kg
                     : A2p + (long)z * a2Slice + (long)(m0 + r) * 512 + (kg - 512);
    }
    gload16(a, ldsA + c * 8);
  }
#pragma unroll
  for (int i = 0; i < 4; i++) {
    const int c = i * 256 + tid;
    const int r = c >> 3;
    const int col = ((c & 7) ^ (r & 7)) << 3;
    gload16(bbase + (long)r * KTOT + (k0 + col), ldsB + c * 8);
  }
}

template <bool CAT, int EPI, int KTOT>
__global__ __launch_bounds__(256, 2)
void gemm64db_k(const us16* __restrict__ Ap, long aSlice,
                const us16* __restrict__ A2p, long a2Slice,
                const us16* __restrict__ Btp, long bSlice,
                const float* __restrict__ bias,
                us16* __restrict__ outB, long outSlice, long outRow,
                const float* __restrict__ dotW, float* __restrict__ partial)
{
  __shared__ us16 lds[2][2][128 * 64];   // [dbuf][A|B][row*64 + col]
  const int tid = threadIdx.x;
  const int z = blockIdx.z;
  const int m0 = blockIdx.x * 128;
  const int n0 = blockIdx.y * 128;
  const int wv = tid >> 6, lane = tid & 63;
  const int wm = (wv >> 1) * 64, wn = (wv & 1) * 64;
  const int fr = lane & 15, fk = (lane >> 4) * 8;
  const int rbase = (lane >> 4) * 4;
  const int xorkey = (fr & 7) << 3;     // read-side swizzle key (elements)

  f32x4 acc[4][4];
#pragma unroll
  for (int i = 0; i < 4; i++)
#pragma unroll
    for (int j = 0; j < 4; j++) acc[i][j] = f32x4{0.f, 0.f, 0.f, 0.f};

  const us16* bbase = Btp + (long)z * bSlice + (long)n0 * KTOT;

  constexpr int NT = KTOT / 64;
  // prologue: stage tile 0 into buffer 0
  stage_tile<CAT, KTOT>(Ap, aSlice, A2p, a2Slice, bbase, z, m0, 0, tid,
                        &lds[0][0][0], &lds[0][1][0]);

#pragma unroll 2
  for (int t = 0; t < NT; ++t) {
    const int d = t & 1;
    if (t + 1 < NT) {
      // prefetch tile t+1 into the other buffer (its reads finished last iter)
      stage_tile<CAT, KTOT>(Ap, aSlice, A2p, a2Slice, bbase, z, m0, (t + 1) * 64,
                            tid, &lds[d ^ 1][0][0], &lds[d ^ 1][1][0]);
      asm volatile("s_waitcnt vmcnt(8)" ::: "memory");   // tile t landed
    } else {
      asm volatile("s_waitcnt vmcnt(0)" ::: "memory");
    }
    __builtin_amdgcn_s_barrier();            // all waves: tile t resident
    __builtin_amdgcn_sched_barrier(0);       // pin ds_reads after the barrier

    const us16* la = &lds[d][0][0];
    const us16* lb = &lds[d][1][0];
    bf16x8 af[2][4], bfg[2][4];
#pragma unroll
    for (int ks = 0; ks < 2; ks++) {
      const int kc = ks * 32 + fk;
#pragma unroll
      for (int f = 0; f < 4; f++)
        af[ks][f]  = *(const bf16x8*)&la[(wm + f * 16 + fr) * 64 + (kc ^ xorkey)];
#pragma unroll
      for (int f = 0; f < 4; f++)
        bfg[ks][f] = *(const bf16x8*)&lb[(wn + f * 16 + fr) * 64 + (kc ^ xorkey)];
    }
    __builtin_amdgcn_s_setprio(1);
#pragma unroll
    for (int ks = 0; ks < 2; ks++)
#pragma unroll
      for (int fm = 0; fm < 4; fm++)
#pragma unroll
        for (int fn = 0; fn < 4; fn++)
          acc[fm][fn] = __builtin_amdgcn_mfma_f32_16x16x32_bf16(af[ks][fm], bfg[ks][fn], acc[fm][fn], 0, 0, 0);
    __builtin_amdgcn_s_setprio(0);
    __builtin_amdgcn_s_barrier();            // reads of buf d done -> next stage may overwrite
    __builtin_amdgcn_sched_barrier(0);       // pin next stage after the barrier
  }

  if constexpr (EPI == EPI_DOT) {
    // hidden = lrelu(acc + bc1[col]); partial[row] += hidden * W2[col]
    const float* bsl = bias + (long)z * 512;
    const float* wsl = dotW + (long)z * 512;
#pragma unroll
    for (int fm = 0; fm < 4; fm++) {
#pragma unroll
      for (int j = 0; j < 4; j++) {
        float p = 0.f;
#pragma unroll
        for (int fn = 0; fn < 4; fn++) {
          int col = n0 + wn + fn * 16 + fr;
          float v = acc[fm][fn][j] + bsl[col];
          v = lrelu(v);
          p += v * wsl[col];
        }
        p += __shfl_xor(p, 1); p += __shfl_xor(p, 2); p += __shfl_xor(p, 4); p += __shfl_xor(p, 8);
        if (fr == 0) {
          long row = (long)z * 8192 + (m0 + wm + fm * 16 + rbase + j);
          partial[row * 8 + blockIdx.y * 2 + (wv & 1)] = p;
        }
      }
    }
  } else {
    // KSV: cols 0-255 raw (key|sel), cols 256-383 get bias+lrelu (vals)
#pragma unroll
    for (int fm = 0; fm < 4; fm++) {
#pragma unroll
      for (int fn = 0; fn < 4; fn++) {
        int col = n0 + wn + fn * 16 + fr;
        float badd = 0.f; bool act = false;
        if (col >= 256) { badd = bias[col - 256]; act = true; }
        us16* op = outB + (long)z * outSlice + (long)(m0 + wm + fm * 16 + rbase) * outRow + col;
#pragma unroll
        for (int j = 0; j < 4; j++) {
          float v = acc[fm][fn][j] + badd;
          if (act) v = lrelu(v);
          op[(long)j * outRow] = f2bf(v);
        }
      }
    }
  }
}

// ---------------------------------------------------------------------------
// Attention: per (b,e): logits = sel_i . key_j / sqrt(128); softmax_j; PV.
// KSV layout [b][n][384] (cols: 0-127 key, 128-255 sel, 256-383 val).
// One wave per b; 4 waves/block; LDS rows padded to 392 (conflict-free dots).
// ---------------------------------------------------------------------------
__global__ __launch_bounds__(256, 2)
void attn_k(const us16* __restrict__ ksv, us16* __restrict__ other, int e)
{
  __shared__ us16 t[4][8 * 392];
  const int wv = threadIdx.x >> 6, lane = threadIdx.x & 63;
  const long b = (long)blockIdx.x * 4 + wv;
  const us16* src = ksv + b * 3072;
#pragma unroll
  for (int i = 0; i < 6; i++) {
    int c = i * 64 + lane;                 // 384 16B-chunks (8 rows x 48)
    int r = c / 48, cc = c - r * 48;
    *(int4*)&t[wv][r * 392 + cc * 8] = *(const int4*)&src[c * 8];
  }
  __syncthreads();
  const int i = lane >> 3, j = lane & 7;   // lane = i*8 + j
  const us16* selp = &t[wv][i * 392 + 128];
  const us16* keyp = &t[wv][j * 392];
  float acc = 0.f;
#pragma unroll
  for (int d = 0; d < 128; d += 8) {
    u16x8 s8 = *(const u16x8*)&selp[d];
    u16x8 k8 = *(const u16x8*)&keyp[d];
#pragma unroll
    for (int q = 0; q < 8; q++) acc += bf2f(s8[q]) * bf2f(k8[q]);
  }
  acc *= 0.088388347648318447f;            // 1/sqrt(128)
  float mx = acc;
  mx = fmaxf(mx, __shfl_xor(mx, 1)); mx = fmaxf(mx, __shfl_xor(mx, 2)); mx = fmaxf(mx, __shfl_xor(mx, 4));
  float ex = __expf(acc - mx);
  float sm = ex;
  sm += __shfl_xor(sm, 1); sm += __shfl_xor(sm, 2); sm += __shfl_xor(sm, 4);
  float wsm = ex / sm;
  float wj[8];
  const int ibase = lane & 56;
#pragma unroll
  for (int jj = 0; jj < 8; jj++) wj[jj] = __shfl(wsm, ibase + jj);
  const int dbase = (lane & 7) * 16;       // this lane: agent i, dims dbase..dbase+15
  float o[16];
#pragma unroll
  for (int q = 0; q < 16; q++) o[q] = 0.f;
#pragma unroll
  for (int jj = 0; jj < 8; jj++) {
    u16x8 v0 = *(const u16x8*)&t[wv][jj * 392 + 256 + dbase];
    u16x8 v1 = *(const u16x8*)&t[wv][jj * 392 + 256 + dbase + 8];
    float wgt = wj[jj];
#pragma unroll
    for (int q = 0; q < 8; q++) { o[q] += wgt * bf2f(v0[q]); o[8 + q] += wgt * bf2f(v1[q]); }
  }
  u16x8 r0, r1;
#pragma unroll
  for (int q = 0; q < 8; q++) { r0[q] = f2bf(o[q]); r1[q] = f2bf(o[8 + q]); }
  us16* dst = other + ((long)i * 8192 + b) * 512 + e * 128 + dbase;
  *(u16x8*)&dst[0] = r0;
  *(u16x8*)&dst[8] = r1;
}

// q[r] = b2[r>>13] + sum of 8 per-block partials
__global__ void reduce_dot_k(const float* __restrict__ part, const float* __restrict__ b2,
                             float* __restrict__ out)
{
  int r = blockIdx.x * 256 + threadIdx.x;  // 0..65535
  const float4* p = (const float4*)(part + (long)r * 8);
  float4 a = p[0], b = p[1];
  out[r] = b2[r >> 13] + ((a.x + a.y) + (a.z + a.w)) + ((b.x + b.y) + (b.z + b.w));
}

// ---------------------------------------------------------------------------
extern "C" void kernel_launch(void* const* d_in, const int* in_sizes, int n_in,
                              void* d_out, int out_size, void* d_ws, size_t ws_size,
                              hipStream_t stream)
{
  const float* states = (const float*)d_in[0];
  const float* actions= (const float*)d_in[1];
  const float* Ws  = (const float*)d_in[2];
  const float* bs  = (const float*)d_in[3];
  const float* Wsa = (const float*)d_in[4];
  const float* bsa = (const float*)d_in[5];
  const float* Wk  = (const float*)d_in[6];
  const float* Wsel= (const float*)d_in[7];
  const float* Wv  = (const float*)d_in[8];
  const float* bv  = (const float*)d_in[9];
  const float* Wc1 = (const float*)d_in[10];
  const float* bc1 = (const float*)d_in[11];
  const float* Wc2 = (const float*)d_in[12];
  const float* bc2 = (const float*)d_in[13];
  const float* Wv1 = (const float*)d_in[14];
  const float* bv1 = (const float*)d_in[15];
  const float* Wv2 = (const float*)d_in[16];
  const float* bv2 = (const float*)d_in[17];

  char* ws = (char*)d_ws;
  constexpr size_t OFF_WST   = 0;
  constexpr size_t OFF_WSAT  = OFF_WST   + (size_t)8 * 512 * 64 * 2;
  constexpr size_t OFF_WKVST = OFF_WSAT  + (size_t)8 * 512 * 96 * 2;
  constexpr size_t OFF_WC1T  = OFF_WKVST + (size_t)4 * 384 * 512 * 2;
  constexpr size_t OFF_WV1T  = OFF_WC1T  + (size_t)8 * 512 * 1024 * 2;
  constexpr size_t OFF_ENC   = OFF_WV1T  + (size_t)8 * 512 * 1024 * 2;
  constexpr size_t OFF_OTHER = OFF_ENC   + (size_t)8 * 8192 * 512 * 2;
  constexpr size_t OFF_KSV   = OFF_OTHER + (size_t)8 * 8192 * 512 * 2;
  constexpr size_t OFF_PART  = OFF_KSV   + (size_t)8192 * 8 * 384 * 2;
  constexpr size_t NEED      = OFF_PART  + (size_t)65536 * 8 * 4;
  if (ws_size < NEED) return;  // workspace too small -> loud validation failure

  us16* WST   = (us16*)(ws + OFF_WST);
  us16* WSAT  = (us16*)(ws + OFF_WSAT);
  us16* WKVST = (us16*)(ws + OFF_WKVST);
  us16* WC1T  = (us16*)(ws + OFF_WC1T);
  us16* WV1T  = (us16*)(ws + OFF_WV1T);
  us16* ENC   = (us16*)(ws + OFF_ENC);    // sa_enc, later reused for s_enc
  us16* OTHER = (us16*)(ws + OFF_OTHER);
  us16* KSV   = (us16*)(ws + OFF_KSV);    // one head at a time: [b][n][384]
  float* PART = (float*)(ws + OFF_PART);

  dim3 tb(32, 8);
  tconv_k<<<dim3(2, 16, 8),  tb, 0, stream>>>(Ws,  (long)64 * 512,  64,  512, WST,  (long)512 * 64,  0,   64,   64);
  tconv_k<<<dim3(3, 16, 8),  tb, 0, stream>>>(Wsa, (long)80 * 512,  80,  512, WSAT, (long)512 * 96,  0,   96,   96);
  tconv_k<<<dim3(16, 4, 4),  tb, 0, stream>>>(Wk,  (long)512 * 128, 512, 128, WKVST,(long)384 * 512, 0,   512,  512);
  tconv_k<<<dim3(16, 4, 4),  tb, 0, stream>>>(Wsel,(long)512 * 128, 512, 128, WKVST,(long)384 * 512, 128, 512,  512);
  tconv_k<<<dim3(16, 4, 4),  tb, 0, stream>>>(Wv,  (long)512 * 128, 512, 128, WKVST,(long)384 * 512, 256, 512,  512);
  tconv_k<<<dim3(32, 16, 8), tb, 0, stream>>>(Wc1, (long)1024 * 512,1024,512, WC1T, (long)512 * 1024,0,   1024, 1024);
  tconv_k<<<dim3(32, 16, 8), tb, 0, stream>>>(Wv1, (long)1024 * 512,1024,512, WV1T, (long)512 * 1024,0,   1024, 1024);

  // sa_enc = lrelu([states|actions] @ Wsa + bsa)  -> ENC (bf16)
  enc_gemm_k<ASRC_F32_CAT, 96><<<dim3(64, 4, 8), 256, 0, stream>>>(
      states, (long)8192 * 64, actions, (long)8192 * 16, WSAT, (long)512 * 96, bsa, 512,
      ENC, (long)8192 * 512, 512);

  // per head: ksv = sa_enc @ [Wk|Wsel|Wv] (+bv,lrelu on vals), then attention
  for (int e = 0; e < 4; e++) {
    gemm64db_k<false, EPI_KSV, 512><<<dim3(64, 3, 8), 256, 0, stream>>>(
        ENC, (long)8192 * 512, nullptr, 0, WKVST + (size_t)e * 384 * 512, 0, bv + e * 128,
        KSV, 384, 3072, nullptr, nullptr);
    attn_k<<<dim3(2048), 256, 0, stream>>>(KSV, OTHER, e);
  }

  // q = lrelu([sa_enc|other] @ Wc1 + bc1) @ Wc2 + bc2
  gemm64db_k<true, EPI_DOT, 1024><<<dim3(64, 4, 8), 256, 0, stream>>>(
      ENC, (long)8192 * 512, OTHER, (long)8192 * 512, WC1T, (long)512 * 1024, bc1,
      nullptr, 0, 0, Wc2, PART);
  reduce_dot_k<<<dim3(256), 256, 0, stream>>>(PART, bc2, (float*)d_out);

  // s_enc = lrelu(states @ Ws + bs) -> ENC (sa_enc is dead now)
  enc_gemm_k<ASRC_F32, 64><<<dim3(64, 4, 8), 256, 0, stream>>>(
      states, (long)8192 * 64, nullptr, 0, WST, (long)512 * 64, bs, 512,
      ENC, (long)8192 * 512, 512);

  // v = lrelu([s_enc|other] @ Wv1 + bv1) @ Wv2 + bv2
  gemm64db_k<true, EPI_DOT, 1024><<<dim3(64, 4, 8), 256, 0, stream>>>(
      ENC, (long)8192 * 512, OTHER, (long)8192 * 512, WV1T, (long)512 * 1024, bv1,
      nullptr, 0, 0, Wv2, PART);
  reduce_dot_k<<<dim3(256), 256, 0, stream>>>(PART, bv2, (float*)d_out + 65536);
}

// Round 5
// 445.126 us; speedup vs baseline: 1.0310x; 1.0310x over previous
//
#include <hip/hip_runtime.h>

// ---------------------------------------------------------------------------
// AttentionCritic on MI355X — round 5: BK=32 double-buffer + counted vmcnt(4)
// at 32 KB LDS / 4 blocks/CU (round-3 occupancy retained), merged transposes.
// N=8 agents, B=8192, S=64, A=16, H=512, E=4 heads, D=128.
// ---------------------------------------------------------------------------

#define DEVI __device__ __forceinline__

typedef unsigned short us16;
typedef __bf16 bf16x8 __attribute__((ext_vector_type(8)));
typedef float f32x4 __attribute__((ext_vector_type(4)));
typedef unsigned short u16x8 __attribute__((ext_vector_type(8)));

DEVI us16 f2bf(float f) {
  unsigned u = __builtin_bit_cast(unsigned, f);
  u += 0x7FFFu + ((u >> 16) & 1u);          // round-to-nearest-even
  return (us16)(u >> 16);
}
DEVI float bf2f(us16 h) {
  unsigned u = ((unsigned)h) << 16;
  return __builtin_bit_cast(float, u);
}
DEVI float lrelu(float v) { return v > 0.f ? v : 0.01f * v; }
DEVI int pk2(float a, float b) { return (int)f2bf(a) | ((int)f2bf(b) << 16); }

// async global->LDS, 16B per lane. LDS dest must be linear: base + lane*16.
DEVI void gload16(const us16* g, us16* l) {
  __builtin_amdgcn_global_load_lds(
      (const __attribute__((address_space(1))) void*)g,
      (__attribute__((address_space(3))) void*)l, 16, 0, 0);
}

// ---------------------------------------------------------------------------
// Transpose + fp32->bf16 convert:  dst[s][dstRowOff+o][k] = src[s][k][o] (k<K else 0)
// block (32,8), grid (Kpad/32, ceil(O/32), slices)
// ---------------------------------------------------------------------------
__global__ void tconv_k(const float* __restrict__ src, long srcSlice, int K, int O,
                        us16* __restrict__ dst, long dstSlice, int dstRowOff,
                        int ldd, int Kpad)
{
  __shared__ float t[32][33];
  const int s = blockIdx.z;
  const int k0 = blockIdx.x * 32, o0 = blockIdx.y * 32;
  const int lx = threadIdx.x, ly = threadIdx.y;
#pragma unroll
  for (int i = 0; i < 4; i++) {
    int k = k0 + ly + i * 8, o = o0 + lx;
    float v = 0.f;
    if (k < K && o < O) v = src[(long)s * srcSlice + (long)k * O + o];
    t[ly + i * 8][lx] = v;
  }
  __syncthreads();
#pragma unroll
  for (int i = 0; i < 4; i++) {
    int o = o0 + ly + i * 8, k = k0 + lx;
    if (o < O && k < Kpad)
      dst[(long)s * dstSlice + (long)(dstRowOff + o) * ldd + k] = f2bf(t[lx][ly + i * 8]);
  }
}

// Merged Wk/Wsel/Wv transpose -> WKVST[e][384][512]. grid (16,4,12), block (32,8).
__global__ void tconv3_k(const float* __restrict__ wk, const float* __restrict__ wsel,
                         const float* __restrict__ wv, us16* __restrict__ dst)
{
  __shared__ float t[32][33];
  const int zz = blockIdx.z;               // 0..11
  const int e = zz & 3, m = zz >> 2;       // m: 0=key 1=sel 2=val
  const float* src = ((m == 0) ? wk : (m == 1) ? wsel : wv) + (long)e * 512 * 128;
  us16* d = dst + (long)e * 384 * 512 + (long)(m * 128) * 512;
  const int k0 = blockIdx.x * 32, o0 = blockIdx.y * 32;
  const int lx = threadIdx.x, ly = threadIdx.y;
#pragma unroll
  for (int i = 0; i < 4; i++)
    t[ly + i * 8][lx] = src[(long)(k0 + ly + i * 8) * 128 + (o0 + lx)];
  __syncthreads();
#pragma unroll
  for (int i = 0; i < 4; i++)
    d[(long)(o0 + ly + i * 8) * 512 + (k0 + lx)] = f2bf(t[lx][ly + i * 8]);
}

// Merged Wc1/Wv1 transpose. grid (32,16,16), block (32,8).
__global__ void tconvC_k(const float* __restrict__ c1, const float* __restrict__ v1,
                         us16* __restrict__ dc, us16* __restrict__ dv)
{
  __shared__ float t[32][33];
  const int zz = blockIdx.z;               // 0..15
  const int n = zz & 7, m = zz >> 3;
  const float* src = ((m == 0) ? c1 : v1) + (long)n * 1024 * 512;
  us16* dst = ((m == 0) ? dc : dv) + (long)n * 512 * 1024;
  const int k0 = blockIdx.x * 32, o0 = blockIdx.y * 32;
  const int lx = threadIdx.x, ly = threadIdx.y;
#pragma unroll
  for (int i = 0; i < 4; i++)
    t[ly + i * 8][lx] = src[(long)(k0 + ly + i * 8) * 512 + (o0 + lx)];
  __syncthreads();
#pragma unroll
  for (int i = 0; i < 4; i++)
    dst[(long)(o0 + ly + i * 8) * 1024 + (k0 + lx)] = f2bf(t[lx][ly + i * 8]);
}

// ---------------------------------------------------------------------------
// fp32-input encoder GEMM (round-2 structure, BK=32, linear LDS).
// C[8192 x 512] = A[8192 x K] * Bt[512 x K]^T, bias + lrelu, bf16 store.
// ---------------------------------------------------------------------------
enum { ASRC_F32 = 2, ASRC_F32_CAT = 3 };

template <int ASRC, int KTOT>
__global__ __launch_bounds__(256, 4)
void enc_gemm_k(const float* __restrict__ Ap, long aSlice,
                const float* __restrict__ A2p, long a2Slice,
                const us16* __restrict__ Btp, long bSlice,
                const float* __restrict__ bias, long biasSlice,
                us16* __restrict__ outB, long outSlice, long outRow)
{
  __shared__ us16 lA[128 * 32];   // linear — required by global_load_lds
  __shared__ us16 lB[128 * 32];
  const int tid = threadIdx.x;
  const int z = blockIdx.z;
  const int m0 = blockIdx.x * 128;
  const int n0 = blockIdx.y * 128;
  const int wv = tid >> 6, lane = tid & 63;
  const int wm = (wv >> 1) * 64, wn = (wv & 1) * 64;
  const int fr = lane & 15, fk = (lane >> 4) * 8;
  const int rbase = (lane >> 4) * 4;
  const int grow = tid >> 2, gcol = (tid & 3) * 8;

  f32x4 acc[4][4];
#pragma unroll
  for (int i = 0; i < 4; i++)
#pragma unroll
    for (int j = 0; j < 4; j++) acc[i][j] = f32x4{0.f, 0.f, 0.f, 0.f};

  const us16* bbase = Btp + (long)z * bSlice + (long)n0 * KTOT;

  for (int k0 = 0; k0 < KTOT; k0 += 32) {
    int4 ra0, ra1;
    {
      const int srow = tid >> 1, scol0 = (tid & 1) * 16;
      const int kg = k0 + scol0;
      const float* a = nullptr;
      if constexpr (ASRC == ASRC_F32) {
        a = Ap + (long)z * aSlice + (long)(m0 + srow) * 64 + kg;
      } else {  // states(0..63) | actions(64..79) | zero pad(80..95)
        if (kg < 64)      a = Ap + (long)z * aSlice + (long)(m0 + srow) * 64 + kg;
        else if (kg < 80) a = A2p + (long)z * a2Slice + (long)(m0 + srow) * 16 + (kg - 64);
      }
      float4 f0, f1, f2, f3;
      if (a) { const float4* ap = (const float4*)a; f0 = ap[0]; f1 = ap[1]; f2 = ap[2]; f3 = ap[3]; }
      else   { f0 = make_float4(0.f, 0.f, 0.f, 0.f); f1 = f0; f2 = f0; f3 = f0; }
      ra0.x = pk2(f0.x, f0.y); ra0.y = pk2(f0.z, f0.w); ra0.z = pk2(f1.x, f1.y); ra0.w = pk2(f1.z, f1.w);
      ra1.x = pk2(f2.x, f2.y); ra1.y = pk2(f2.z, f2.w); ra1.z = pk2(f3.x, f3.y); ra1.w = pk2(f3.z, f3.w);
    }

    __syncthreads();
    {
      const us16* bb = bbase + k0 + gcol;
      gload16(bb + (long)grow * KTOT, &lB[tid * 8]);
      gload16(bb + (long)(64 + grow) * KTOT, &lB[2048 + tid * 8]);
    }
    {
      const int srow = tid >> 1, scol0 = (tid & 1) * 16;
      *(int4*)&lA[srow * 32 + scol0]     = ra0;
      *(int4*)&lA[srow * 32 + scol0 + 8] = ra1;
    }
    __syncthreads();

    bf16x8 af[4], bfg[4];
#pragma unroll
    for (int f = 0; f < 4; f++) af[f]  = *(const bf16x8*)&lA[(wm + f * 16 + fr) * 32 + fk];
#pragma unroll
    for (int f = 0; f < 4; f++) bfg[f] = *(const bf16x8*)&lB[(wn + f * 16 + fr) * 32 + fk];
#pragma unroll
    for (int fm = 0; fm < 4; fm++)
#pragma unroll
      for (int fn = 0; fn < 4; fn++)
        acc[fm][fn] = __builtin_amdgcn_mfma_f32_16x16x32_bf16(af[fm], bfg[fn], acc[fm][fn], 0, 0, 0);
  }

#pragma unroll
  for (int fm = 0; fm < 4; fm++) {
#pragma unroll
    for (int fn = 0; fn < 4; fn++) {
      int col = n0 + wn + fn * 16 + fr;
      float badd = bias[(long)z * biasSlice + col];
      us16* op = outB + (long)z * outSlice + (long)(m0 + wm + fm * 16 + rbase) * outRow + col;
#pragma unroll
      for (int j = 0; j < 4; j++) {
        float v = lrelu(acc[fm][fn][j] + badd);
        op[(long)j * outRow] = f2bf(v);
      }
    }
  }
}

// ---------------------------------------------------------------------------
// bf16 MFMA GEMM, BK=32 DOUBLE-BUFFERED, counted vmcnt(4), 32 KB LDS.
// Swizzle: 16B chunk j of row r stored from source chunk (j ^ ((r>>1)&3));
// read addr = row*32 + (fk ^ (((row>>1)&3)<<3)). 2-way banks = free.
// Per iter: 4 gloads (t+1) -> vmcnt(4) -> barrier -> 8 ds_read_b128 + 16 MFMA
// -> barrier. Loads never drained to 0 in the main loop.
// ---------------------------------------------------------------------------
enum { EPI_KSV = 1, EPI_DOT = 2 };

template <bool CAT, int KTOT>
DEVI void stage32(const us16* __restrict__ Ap, long aSlice,
                  const us16* __restrict__ A2p, long a2Slice,
                  const us16* __restrict__ bbase, int z, int m0, int k0,
                  int tid, us16* ldsA, us16* ldsB)
{
#pragma unroll
  for (int i = 0; i < 2; i++) {
    const int c = i * 256 + tid;               // 16B chunk 0..511
    const int r = c >> 2;                      // tile row 0..127
    const int col = ((c & 3) ^ ((r >> 1) & 3)) << 3;
    const us16* a;
    if constexpr (!CAT) {
      a = Ap + (long)z * aSlice + (long)(m0 + r) * KTOT + (k0 + col);
    } else {
      const int kg = k0 + col;                 // 8-elem chunks never straddle 512
      a = (kg < 512) ? Ap  + (long)z * aSlice  + (long)(m0 + r) * 512 + kg
                     : A2p + (long)z * a2Slice + (long)(m0 + r) * 512 + (kg - 512);
    }
    gload16(a, ldsA + c * 8);
  }
#pragma unroll
  for (int i = 0; i < 2; i++) {
    const int c = i * 256 + tid;
    const int r = c >> 2;
    const int col = ((c & 3) ^ ((r >> 1) & 3)) << 3;
    gload16(bbase + (long)r * KTOT + (k0 + col), ldsB + c * 8);
  }
}

template <bool CAT, int EPI, int KTOT>
__global__ __launch_bounds__(256, 4)
void gemm32db_k(const us16* __restrict__ Ap, long aSlice,
                const us16* __restrict__ A2p, long a2Slice,
                const us16* __restrict__ Btp, long bSlice,
                const float* __restrict__ bias,
                us16* __restrict__ outB, long outSlice, long outRow,
                const float* __restrict__ dotW, float* __restrict__ partial)
{
  __shared__ us16 lds[2][2][128 * 32];   // [dbuf][A|B] = 32 KB total
  const int tid = threadIdx.x;
  const int z = blockIdx.z;
  const int m0 = blockIdx.x * 128;
  const int n0 = blockIdx.y * 128;
  const int wv = tid >> 6, lane = tid & 63;
  const int wm = (wv >> 1) * 64, wn = (wv & 1) * 64;
  const int fr = lane & 15, fk = (lane >> 4) * 8;
  const int rbase = (lane >> 4) * 4;
  const int xorkey = ((fr >> 1) & 3) << 3;   // read-side swizzle key (elements)

  f32x4 acc[4][4];
#pragma unroll
  for (int i = 0; i < 4; i++)
#pragma unroll
    for (int j = 0; j < 4; j++) acc[i][j] = f32x4{0.f, 0.f, 0.f, 0.f};

  const us16* bbase = Btp + (long)z * bSlice + (long)n0 * KTOT;

  constexpr int NT = KTOT / 32;
  // prologue: stage tile 0 into buffer 0
  stage32<CAT, KTOT>(Ap, aSlice, A2p, a2Slice, bbase, z, m0, 0, tid,
                     &lds[0][0][0], &lds[0][1][0]);

#pragma unroll 2
  for (int t = 0; t < NT - 1; ++t) {
    const int d = t & 1;
    // prefetch tile t+1 into the other buffer (its reads fenced last iter)
    stage32<CAT, KTOT>(Ap, aSlice, A2p, a2Slice, bbase, z, m0, (t + 1) * 32,
                       tid, &lds[d ^ 1][0][0], &lds[d ^ 1][1][0]);
    asm volatile("s_waitcnt vmcnt(4)" ::: "memory");   // tile t landed; t+1 in flight
    __builtin_amdgcn_s_barrier();
    __builtin_amdgcn_sched_barrier(0);

    const us16* la = &lds[d][0][0];
    const us16* lb = &lds[d][1][0];
    bf16x8 af[4], bfg[4];
#pragma unroll
    for (int f = 0; f < 4; f++)
      af[f]  = *(const bf16x8*)&la[(wm + f * 16 + fr) * 32 + (fk ^ xorkey)];
#pragma unroll
    for (int f = 0; f < 4; f++)
      bfg[f] = *(const bf16x8*)&lb[(wn + f * 16 + fr) * 32 + (fk ^ xorkey)];
    __builtin_amdgcn_s_setprio(1);
#pragma unroll
    for (int fm = 0; fm < 4; fm++)
#pragma unroll
      for (int fn = 0; fn < 4; fn++)
        acc[fm][fn] = __builtin_amdgcn_mfma_f32_16x16x32_bf16(af[fm], bfg[fn], acc[fm][fn], 0, 0, 0);
    __builtin_amdgcn_s_setprio(0);
    __builtin_amdgcn_s_barrier();            // reads of buf d done -> t+2 stage may overwrite
    __builtin_amdgcn_sched_barrier(0);
  }
  {  // final tile, buffer (NT-1)&1
    asm volatile("s_waitcnt vmcnt(0)" ::: "memory");
    __builtin_amdgcn_s_barrier();
    __builtin_amdgcn_sched_barrier(0);
    const us16* la = &lds[(NT - 1) & 1][0][0];
    const us16* lb = &lds[(NT - 1) & 1][1][0];
    bf16x8 af[4], bfg[4];
#pragma unroll
    for (int f = 0; f < 4; f++)
      af[f]  = *(const bf16x8*)&la[(wm + f * 16 + fr) * 32 + (fk ^ xorkey)];
#pragma unroll
    for (int f = 0; f < 4; f++)
      bfg[f] = *(const bf16x8*)&lb[(wn + f * 16 + fr) * 32 + (fk ^ xorkey)];
#pragma unroll
    for (int fm = 0; fm < 4; fm++)
#pragma unroll
      for (int fn = 0; fn < 4; fn++)
        acc[fm][fn] = __builtin_amdgcn_mfma_f32_16x16x32_bf16(af[fm], bfg[fn], acc[fm][fn], 0, 0, 0);
  }

  if constexpr (EPI == EPI_DOT) {
    // hidden = lrelu(acc + bc1[col]); partial[row] += hidden * W2[col]
    const float* bsl = bias + (long)z * 512;
    const float* wsl = dotW + (long)z * 512;
#pragma unroll
    for (int fm = 0; fm < 4; fm++) {
#pragma unroll
      for (int j = 0; j < 4; j++) {
        float p = 0.f;
#pragma unroll
        for (int fn = 0; fn < 4; fn++) {
          int col = n0 + wn + fn * 16 + fr;
          float v = acc[fm][fn][j] + bsl[col];
          v = lrelu(v);
          p += v * wsl[col];
        }
        p += __shfl_xor(p, 1); p += __shfl_xor(p, 2); p += __shfl_xor(p, 4); p += __shfl_xor(p, 8);
        if (fr == 0) {
          long row = (long)z * 8192 + (m0 + wm + fm * 16 + rbase + j);
          partial[row * 8 + blockIdx.y * 2 + (wv & 1)] = p;
        }
      }
    }
  } else {
    // KSV: cols 0-255 raw (key|sel), cols 256-383 get bias+lrelu (vals)
#pragma unroll
    for (int fm = 0; fm < 4; fm++) {
#pragma unroll
      for (int fn = 0; fn < 4; fn++) {
        int col = n0 + wn + fn * 16 + fr;
        float badd = 0.f; bool act = false;
        if (col >= 256) { badd = bias[col - 256]; act = true; }
        us16* op = outB + (long)z * outSlice + (long)(m0 + wm + fm * 16 + rbase) * outRow + col;
#pragma unroll
        for (int j = 0; j < 4; j++) {
          float v = acc[fm][fn][j] + badd;
          if (act) v = lrelu(v);
          op[(long)j * outRow] = f2bf(v);
        }
      }
    }
  }
}

// ---------------------------------------------------------------------------
// Attention: per (b,e): logits = sel_i . key_j / sqrt(128); softmax_j; PV.
// KSV layout [b][n][384] (cols: 0-127 key, 128-255 sel, 256-383 val).
// One wave per b; 4 waves/block; LDS rows padded to 392 (conflict-free dots).
// ---------------------------------------------------------------------------
__global__ __launch_bounds__(256, 2)
void attn_k(const us16* __restrict__ ksv, us16* __restrict__ other, int e)
{
  __shared__ us16 t[4][8 * 392];
  const int wv = threadIdx.x >> 6, lane = threadIdx.x & 63;
  const long b = (long)blockIdx.x * 4 + wv;
  const us16* src = ksv + b * 3072;
#pragma unroll
  for (int i = 0; i < 6; i++) {
    int c = i * 64 + lane;                 // 384 16B-chunks (8 rows x 48)
    int r = c / 48, cc = c - r * 48;
    *(int4*)&t[wv][r * 392 + cc * 8] = *(const int4*)&src[c * 8];
  }
  __syncthreads();
  const int i = lane >> 3, j = lane & 7;   // lane = i*8 + j
  const us16* selp = &t[wv][i * 392 + 128];
  const us16* keyp = &t[wv][j * 392];
  float acc = 0.f;
#pragma unroll
  for (int d = 0; d < 128; d += 8) {
    u16x8 s8 = *(const u16x8*)&selp[d];
    u16x8 k8 = *(const u16x8*)&keyp[d];
#pragma unroll
    for (int q = 0; q < 8; q++) acc += bf2f(s8[q]) * bf2f(k8[q]);
  }
  acc *= 0.088388347648318447f;            // 1/sqrt(128)
  float mx = acc;
  mx = fmaxf(mx, __shfl_xor(mx, 1)); mx = fmaxf(mx, __shfl_xor(mx, 2)); mx = fmaxf(mx, __shfl_xor(mx, 4));
  float ex = __expf(acc - mx);
  float sm = ex;
  sm += __shfl_xor(sm, 1); sm += __shfl_xor(sm, 2); sm += __shfl_xor(sm, 4);
  float wsm = ex / sm;
  float wj[8];
  const int ibase = lane & 56;
#pragma unroll
  for (int jj = 0; jj < 8; jj++) wj[jj] = __shfl(wsm, ibase + jj);
  const int dbase = (lane & 7) * 16;       // this lane: agent i, dims dbase..dbase+15
  float o[16];
#pragma unroll
  for (int q = 0; q < 16; q++) o[q] = 0.f;
#pragma unroll
  for (int jj = 0; jj < 8; jj++) {
    u16x8 v0 = *(const u16x8*)&t[wv][jj * 392 + 256 + dbase];
    u16x8 v1 = *(const u16x8*)&t[wv][jj * 392 + 256 + dbase + 8];
    float wgt = wj[jj];
#pragma unroll
    for (int q = 0; q < 8; q++) { o[q] += wgt * bf2f(v0[q]); o[8 + q] += wgt * bf2f(v1[q]); }
  }
  u16x8 r0, r1;
#pragma unroll
  for (int q = 0; q < 8; q++) { r0[q] = f2bf(o[q]); r1[q] = f2bf(o[8 + q]); }
  us16* dst = other + ((long)i * 8192 + b) * 512 + e * 128 + dbase;
  *(u16x8*)&dst[0] = r0;
  *(u16x8*)&dst[8] = r1;
}

// q[r] = b2[r>>13] + sum of 8 per-block partials
__global__ void reduce_dot_k(const float* __restrict__ part, const float* __restrict__ b2,
                             float* __restrict__ out)
{
  int r = blockIdx.x * 256 + threadIdx.x;  // 0..65535
  const float4* p = (const float4*)(part + (long)r * 8);
  float4 a = p[0], b = p[1];
  out[r] = b2[r >> 13] + ((a.x + a.y) + (a.z + a.w)) + ((b.x + b.y) + (b.z + b.w));
}

// ---------------------------------------------------------------------------
extern "C" void kernel_launch(void* const* d_in, const int* in_sizes, int n_in,
                              void* d_out, int out_size, void* d_ws, size_t ws_size,
                              hipStream_t stream)
{
  const float* states = (const float*)d_in[0];
  const float* actions= (const float*)d_in[1];
  const float* Ws  = (const float*)d_in[2];
  const float* bs  = (const float*)d_in[3];
  const float* Wsa = (const float*)d_in[4];
  const float* bsa = (const float*)d_in[5];
  const float* Wk  = (const float*)d_in[6];
  const float* Wsel= (const float*)d_in[7];
  const float* Wv  = (const float*)d_in[8];
  const float* bv  = (const float*)d_in[9];
  const float* Wc1 = (const float*)d_in[10];
  const float* bc1 = (const float*)d_in[11];
  const float* Wc2 = (const float*)d_in[12];
  const float* bc2 = (const float*)d_in[13];
  const float* Wv1 = (const float*)d_in[14];
  const float* bv1 = (const float*)d_in[15];
  const float* Wv2 = (const float*)d_in[16];
  const float* bv2 = (const float*)d_in[17];

  char* ws = (char*)d_ws;
  constexpr size_t OFF_WST   = 0;
  constexpr size_t OFF_WSAT  = OFF_WST   + (size_t)8 * 512 * 64 * 2;
  constexpr size_t OFF_WKVST = OFF_WSAT  + (size_t)8 * 512 * 96 * 2;
  constexpr size_t OFF_WC1T  = OFF_WKVST + (size_t)4 * 384 * 512 * 2;
  constexpr size_t OFF_WV1T  = OFF_WC1T  + (size_t)8 * 512 * 1024 * 2;
  constexpr size_t OFF_ENC   = OFF_WV1T  + (size_t)8 * 512 * 1024 * 2;
  constexpr size_t OFF_OTHER = OFF_ENC   + (size_t)8 * 8192 * 512 * 2;
  constexpr size_t OFF_KSV   = OFF_OTHER + (size_t)8 * 8192 * 512 * 2;
  constexpr size_t OFF_PART  = OFF_KSV   + (size_t)8192 * 8 * 384 * 2;
  constexpr size_t NEED      = OFF_PART  + (size_t)65536 * 8 * 4;
  if (ws_size < NEED) return;  // workspace too small -> loud validation failure

  us16* WST   = (us16*)(ws + OFF_WST);
  us16* WSAT  = (us16*)(ws + OFF_WSAT);
  us16* WKVST = (us16*)(ws + OFF_WKVST);
  us16* WC1T  = (us16*)(ws + OFF_WC1T);
  us16* WV1T  = (us16*)(ws + OFF_WV1T);
  us16* ENC   = (us16*)(ws + OFF_ENC);    // sa_enc, later reused for s_enc
  us16* OTHER = (us16*)(ws + OFF_OTHER);
  us16* KSV   = (us16*)(ws + OFF_KSV);    // one head at a time: [b][n][384]
  float* PART = (float*)(ws + OFF_PART);

  dim3 tb(32, 8);
  tconv_k <<<dim3(2, 16, 8),  tb, 0, stream>>>(Ws,  (long)64 * 512, 64, 512, WST,  (long)512 * 64, 0, 64, 64);
  tconv_k <<<dim3(3, 16, 8),  tb, 0, stream>>>(Wsa, (long)80 * 512, 80, 512, WSAT, (long)512 * 96, 0, 96, 96);
  tconv3_k<<<dim3(16, 4, 12), tb, 0, stream>>>(Wk, Wsel, Wv, WKVST);
  tconvC_k<<<dim3(32, 16, 16),tb, 0, stream>>>(Wc1, Wv1, WC1T, WV1T);

  // sa_enc = lrelu([states|actions] @ Wsa + bsa)  -> ENC (bf16)
  enc_gemm_k<ASRC_F32_CAT, 96><<<dim3(64, 4, 8), 256, 0, stream>>>(
      states, (long)8192 * 64, actions, (long)8192 * 16, WSAT, (long)512 * 96, bsa, 512,
      ENC, (long)8192 * 512, 512);

  // per head: ksv = sa_enc @ [Wk|Wsel|Wv] (+bv,lrelu on vals), then attention
  for (int e = 0; e < 4; e++) {
    gemm32db_k<false, EPI_KSV, 512><<<dim3(64, 3, 8), 256, 0, stream>>>(
        ENC, (long)8192 * 512, nullptr, 0, WKVST + (size_t)e * 384 * 512, 0, bv + e * 128,
        KSV, 384, 3072, nullptr, nullptr);
    attn_k<<<dim3(2048), 256, 0, stream>>>(KSV, OTHER, e);
  }

  // q = lrelu([sa_enc|other] @ Wc1 + bc1) @ Wc2 + bc2
  gemm32db_k<true, EPI_DOT, 1024><<<dim3(64, 4, 8), 256, 0, stream>>>(
      ENC, (long)8192 * 512, OTHER, (long)8192 * 512, WC1T, (long)512 * 1024, bc1,
      nullptr, 0, 0, Wc2, PART);
  reduce_dot_k<<<dim3(256), 256, 0, stream>>>(PART, bc2, (float*)d_out);

  // s_enc = lrelu(states @ Ws + bs) -> ENC (sa_enc is dead now)
  enc_gemm_k<ASRC_F32, 64><<<dim3(64, 4, 8), 256, 0, stream>>>(
      states, (long)8192 * 64, nullptr, 0, WST, (long)512 * 64, bs, 512,
      ENC, (long)8192 * 512, 512);

  // v = lrelu([s_enc|other] @ Wv1 + bv1) @ Wv2 + bv2
  gemm32db_k<true, EPI_DOT, 1024><<<dim3(64, 4, 8), 256, 0, stream>>>(
      ENC, (long)8192 * 512, OTHER, (long)8192 * 512, WV1T, (long)512 * 1024, bv1,
      nullptr, 0, 0, Wv2, PART);
  reduce_dot_k<<<dim3(256), 256, 0, stream>>>(PART, bv2, (float*)d_out + 65536);
}

// Round 7
// 440.671 us; speedup vs baseline: 1.0415x; 1.0101x over previous
//
#include <hip/hip_runtime.h>

// ---------------------------------------------------------------------------
// AttentionCritic on MI355X — round 7: round-6 plan with the LDS pointer-array
// compile error fixed (scalar offset arithmetic instead of pointer arrays).
// 256^2 8-wave phase-interleaved GEMM (m201 template) for the two K=1024 MLP
// GEMMs; everything else = round 3.
// ---------------------------------------------------------------------------

#define DEVI __device__ __forceinline__

typedef unsigned short us16;
typedef __bf16 bf16x8 __attribute__((ext_vector_type(8)));
typedef float f32x4 __attribute__((ext_vector_type(4)));
typedef unsigned short u16x8 __attribute__((ext_vector_type(8)));

DEVI us16 f2bf(float f) {
  unsigned u = __builtin_bit_cast(unsigned, f);
  u += 0x7FFFu + ((u >> 16) & 1u);          // round-to-nearest-even
  return (us16)(u >> 16);
}
DEVI float bf2f(us16 h) {
  unsigned u = ((unsigned)h) << 16;
  return __builtin_bit_cast(float, u);
}
DEVI float lrelu(float v) { return v > 0.f ? v : 0.01f * v; }
DEVI int pk2(float a, float b) { return (int)f2bf(a) | ((int)f2bf(b) << 16); }

// async global->LDS, 16B per lane. LDS dest must be linear: base + lane*16.
DEVI void gload16(const us16* g, us16* l) {
  __builtin_amdgcn_global_load_lds(
      (const __attribute__((address_space(1))) void*)g,
      (__attribute__((address_space(3))) void*)l, 16, 0, 0);
}

// ---------------------------------------------------------------------------
// Transpose + fp32->bf16 convert kernels
// ---------------------------------------------------------------------------
__global__ void tconv_k(const float* __restrict__ src, long srcSlice, int K, int O,
                        us16* __restrict__ dst, long dstSlice, int dstRowOff,
                        int ldd, int Kpad)
{
  __shared__ float t[32][33];
  const int s = blockIdx.z;
  const int k0 = blockIdx.x * 32, o0 = blockIdx.y * 32;
  const int lx = threadIdx.x, ly = threadIdx.y;
#pragma unroll
  for (int i = 0; i < 4; i++) {
    int k = k0 + ly + i * 8, o = o0 + lx;
    float v = 0.f;
    if (k < K && o < O) v = src[(long)s * srcSlice + (long)k * O + o];
    t[ly + i * 8][lx] = v;
  }
  __syncthreads();
#pragma unroll
  for (int i = 0; i < 4; i++) {
    int o = o0 + ly + i * 8, k = k0 + lx;
    if (o < O && k < Kpad)
      dst[(long)s * dstSlice + (long)(dstRowOff + o) * ldd + k] = f2bf(t[lx][ly + i * 8]);
  }
}

// Merged Wk/Wsel/Wv transpose -> WKVST[e][384][512]. grid (16,4,12), block (32,8).
__global__ void tconv3_k(const float* __restrict__ wk, const float* __restrict__ wsel,
                         const float* __restrict__ wv, us16* __restrict__ dst)
{
  __shared__ float t[32][33];
  const int zz = blockIdx.z;               // 0..11
  const int e = zz & 3, m = zz >> 2;       // m: 0=key 1=sel 2=val
  const float* src = ((m == 0) ? wk : (m == 1) ? wsel : wv) + (long)e * 512 * 128;
  us16* d = dst + (long)e * 384 * 512 + (long)(m * 128) * 512;
  const int k0 = blockIdx.x * 32, o0 = blockIdx.y * 32;
  const int lx = threadIdx.x, ly = threadIdx.y;
#pragma unroll
  for (int i = 0; i < 4; i++)
    t[ly + i * 8][lx] = src[(long)(k0 + ly + i * 8) * 128 + (o0 + lx)];
  __syncthreads();
#pragma unroll
  for (int i = 0; i < 4; i++)
    d[(long)(o0 + ly + i * 8) * 512 + (k0 + lx)] = f2bf(t[lx][ly + i * 8]);
}

// Merged Wc1/Wv1 transpose. grid (32,16,16), block (32,8).
__global__ void tconvC_k(const float* __restrict__ c1, const float* __restrict__ v1,
                         us16* __restrict__ dc, us16* __restrict__ dv)
{
  __shared__ float t[32][33];
  const int zz = blockIdx.z;               // 0..15
  const int n = zz & 7, m = zz >> 3;
  const float* src = ((m == 0) ? c1 : v1) + (long)n * 1024 * 512;
  us16* dst = ((m == 0) ? dc : dv) + (long)n * 512 * 1024;
  const int k0 = blockIdx.x * 32, o0 = blockIdx.y * 32;
  const int lx = threadIdx.x, ly = threadIdx.y;
#pragma unroll
  for (int i = 0; i < 4; i++)
    t[ly + i * 8][lx] = src[(long)(k0 + ly + i * 8) * 512 + (o0 + lx)];
  __syncthreads();
#pragma unroll
  for (int i = 0; i < 4; i++)
    dst[(long)(o0 + ly + i * 8) * 1024 + (k0 + lx)] = f2bf(t[lx][ly + i * 8]);
}

// ---------------------------------------------------------------------------
// fp32-input encoder GEMM (round-2/3 structure, BK=32, linear LDS). Proven.
// ---------------------------------------------------------------------------
enum { ASRC_F32 = 2, ASRC_F32_CAT = 3 };

template <int ASRC, int KTOT>
__global__ __launch_bounds__(256, 4)
void enc_gemm_k(const float* __restrict__ Ap, long aSlice,
                const float* __restrict__ A2p, long a2Slice,
                const us16* __restrict__ Btp, long bSlice,
                const float* __restrict__ bias, long biasSlice,
                us16* __restrict__ outB, long outSlice, long outRow)
{
  __shared__ us16 lA[128 * 32];
  __shared__ us16 lB[128 * 32];
  const int tid = threadIdx.x;
  const int z = blockIdx.z;
  const int m0 = blockIdx.x * 128;
  const int n0 = blockIdx.y * 128;
  const int wv = tid >> 6, lane = tid & 63;
  const int wm = (wv >> 1) * 64, wn = (wv & 1) * 64;
  const int fr = lane & 15, fk = (lane >> 4) * 8;
  const int rbase = (lane >> 4) * 4;
  const int grow = tid >> 2, gcol = (tid & 3) * 8;

  f32x4 acc[4][4];
#pragma unroll
  for (int i = 0; i < 4; i++)
#pragma unroll
    for (int j = 0; j < 4; j++) acc[i][j] = f32x4{0.f, 0.f, 0.f, 0.f};

  const us16* bbase = Btp + (long)z * bSlice + (long)n0 * KTOT;

  for (int k0 = 0; k0 < KTOT; k0 += 32) {
    int4 ra0, ra1;
    {
      const int srow = tid >> 1, scol0 = (tid & 1) * 16;
      const int kg = k0 + scol0;
      const float* a = nullptr;
      if constexpr (ASRC == ASRC_F32) {
        a = Ap + (long)z * aSlice + (long)(m0 + srow) * 64 + kg;
      } else {  // states(0..63) | actions(64..79) | zero pad(80..95)
        if (kg < 64)      a = Ap + (long)z * aSlice + (long)(m0 + srow) * 64 + kg;
        else if (kg < 80) a = A2p + (long)z * a2Slice + (long)(m0 + srow) * 16 + (kg - 64);
      }
      float4 f0, f1, f2, f3;
      if (a) { const float4* ap = (const float4*)a; f0 = ap[0]; f1 = ap[1]; f2 = ap[2]; f3 = ap[3]; }
      else   { f0 = make_float4(0.f, 0.f, 0.f, 0.f); f1 = f0; f2 = f0; f3 = f0; }
      ra0.x = pk2(f0.x, f0.y); ra0.y = pk2(f0.z, f0.w); ra0.z = pk2(f1.x, f1.y); ra0.w = pk2(f1.z, f1.w);
      ra1.x = pk2(f2.x, f2.y); ra1.y = pk2(f2.z, f2.w); ra1.z = pk2(f3.x, f3.y); ra1.w = pk2(f3.z, f3.w);
    }

    __syncthreads();
    {
      const us16* bb = bbase + k0 + gcol;
      gload16(bb + (long)grow * KTOT, &lB[tid * 8]);
      gload16(bb + (long)(64 + grow) * KTOT, &lB[2048 + tid * 8]);
    }
    {
      const int srow = tid >> 1, scol0 = (tid & 1) * 16;
      *(int4*)&lA[srow * 32 + scol0]     = ra0;
      *(int4*)&lA[srow * 32 + scol0 + 8] = ra1;
    }
    __syncthreads();

    bf16x8 af[4], bfg[4];
#pragma unroll
    for (int f = 0; f < 4; f++) af[f]  = *(const bf16x8*)&lA[(wm + f * 16 + fr) * 32 + fk];
#pragma unroll
    for (int f = 0; f < 4; f++) bfg[f] = *(const bf16x8*)&lB[(wn + f * 16 + fr) * 32 + fk];
#pragma unroll
    for (int fm = 0; fm < 4; fm++)
#pragma unroll
      for (int fn = 0; fn < 4; fn++)
        acc[fm][fn] = __builtin_amdgcn_mfma_f32_16x16x32_bf16(af[fm], bfg[fn], acc[fm][fn], 0, 0, 0);
  }

#pragma unroll
  for (int fm = 0; fm < 4; fm++) {
#pragma unroll
    for (int fn = 0; fn < 4; fn++) {
      int col = n0 + wn + fn * 16 + fr;
      float badd = bias[(long)z * biasSlice + col];
      us16* op = outB + (long)z * outSlice + (long)(m0 + wm + fm * 16 + rbase) * outRow + col;
#pragma unroll
      for (int j = 0; j < 4; j++) {
        float v = lrelu(acc[fm][fn][j] + badd);
        op[(long)j * outRow] = f2bf(v);
      }
    }
  }
}

// ---------------------------------------------------------------------------
// Round-3 proven 128^2 GEMM (BK=64, XOR-swizzle, 2-barrier). Used for KSV and
// as the deterministic fallback for the MLP GEMMs if 128 KiB dyn-LDS is denied.
// ---------------------------------------------------------------------------
enum { EPI_KSV = 1, EPI_DOT = 2 };

template <bool CAT, int EPI, int KTOT>
__global__ __launch_bounds__(256, 4)
void gemm64_k(const us16* __restrict__ Ap, long aSlice,
              const us16* __restrict__ A2p, long a2Slice,
              const us16* __restrict__ Btp, long bSlice,
              const float* __restrict__ bias,
              us16* __restrict__ outB, long outSlice, long outRow,
              const float* __restrict__ dotW, float* __restrict__ partial)
{
  __shared__ us16 lA[128 * 64];
  __shared__ us16 lB[128 * 64];
  const int tid = threadIdx.x;
  const int z = blockIdx.z;
  const int m0 = blockIdx.x * 128;
  const int n0 = blockIdx.y * 128;
  const int wv = tid >> 6, lane = tid & 63;
  const int wm = (wv >> 1) * 64, wn = (wv & 1) * 64;
  const int fr = lane & 15, fk = (lane >> 4) * 8;
  const int rbase = (lane >> 4) * 4;
  const int xorkey = (fr & 7) << 3;

  f32x4 acc[4][4];
#pragma unroll
  for (int i = 0; i < 4; i++)
#pragma unroll
    for (int j = 0; j < 4; j++) acc[i][j] = f32x4{0.f, 0.f, 0.f, 0.f};

  const us16* bbase = Btp + (long)z * bSlice + (long)n0 * KTOT;

  for (int k0 = 0; k0 < KTOT; k0 += 64) {
    __syncthreads();
#pragma unroll
    for (int i = 0; i < 4; i++) {
      const int c = i * 256 + tid;
      const int r = c >> 3;
      const int col = ((c & 7) ^ (r & 7)) << 3;
      const us16* a;
      if constexpr (!CAT) {
        a = Ap + (long)z * aSlice + (long)(m0 + r) * KTOT + (k0 + col);
      } else {
        const int kg = k0 + col;
        a = (kg < 512) ? Ap  + (long)z * aSlice  + (long)(m0 + r) * 512 + kg
                       : A2p + (long)z * a2Slice + (long)(m0 + r) * 512 + (kg - 512);
      }
      gload16(a, &lA[c * 8]);
    }
#pragma unroll
    for (int i = 0; i < 4; i++) {
      const int c = i * 256 + tid;
      const int r = c >> 3;
      const int col = ((c & 7) ^ (r & 7)) << 3;
      gload16(bbase + (long)r * KTOT + (k0 + col), &lB[c * 8]);
    }
    __syncthreads();

#pragma unroll
    for (int ks = 0; ks < 2; ks++) {
      bf16x8 af[4], bfg[4];
      const int kc = ks * 32 + fk;
#pragma unroll
      for (int f = 0; f < 4; f++)
        af[f]  = *(const bf16x8*)&lA[(wm + f * 16 + fr) * 64 + (kc ^ xorkey)];
#pragma unroll
      for (int f = 0; f < 4; f++)
        bfg[f] = *(const bf16x8*)&lB[(wn + f * 16 + fr) * 64 + (kc ^ xorkey)];
#pragma unroll
      for (int fm = 0; fm < 4; fm++)
#pragma unroll
        for (int fn = 0; fn < 4; fn++)
          acc[fm][fn] = __builtin_amdgcn_mfma_f32_16x16x32_bf16(af[fm], bfg[fn], acc[fm][fn], 0, 0, 0);
    }
  }

  if constexpr (EPI == EPI_DOT) {
    const float* bsl = bias + (long)z * 512;
    const float* wsl = dotW + (long)z * 512;
#pragma unroll
    for (int fm = 0; fm < 4; fm++) {
#pragma unroll
      for (int j = 0; j < 4; j++) {
        float p = 0.f;
#pragma unroll
        for (int fn = 0; fn < 4; fn++) {
          int col = n0 + wn + fn * 16 + fr;
          float v = acc[fm][fn][j] + bsl[col];
          v = lrelu(v);
          p += v * wsl[col];
        }
        p += __shfl_xor(p, 1); p += __shfl_xor(p, 2); p += __shfl_xor(p, 4); p += __shfl_xor(p, 8);
        if (fr == 0) {
          long row = (long)z * 8192 + (m0 + wm + fm * 16 + rbase + j);
          partial[row * 8 + blockIdx.y * 2 + (wv & 1)] = p;
        }
      }
    }
  } else {
#pragma unroll
    for (int fm = 0; fm < 4; fm++) {
#pragma unroll
      for (int fn = 0; fn < 4; fn++) {
        int col = n0 + wn + fn * 16 + fr;
        float badd = 0.f; bool act = false;
        if (col >= 256) { badd = bias[col - 256]; act = true; }
        us16* op = outB + (long)z * outSlice + (long)(m0 + wm + fm * 16 + rbase) * outRow + col;
#pragma unroll
        for (int j = 0; j < 4; j++) {
          float v = acc[fm][fn][j] + badd;
          if (act) v = lrelu(v);
          op[(long)j * outRow] = f2bf(v);
        }
      }
    }
  }
}

// ---------------------------------------------------------------------------
// 256^2 8-wave phase-interleaved GEMM (m201 template, plain HIP).
// BM=BN=256, BK=64, 512 threads = 8 waves (2M x 4N), per-wave out 128x64.
// LDS 128 KiB dynamic: offsets dbuf*32768 + {A:0 | B:16384}. XOR-swizzle.
// Per K-tile: {stage gloads(t+1) g=0; vmcnt(2); barrier} then 4 phases of
// {ds_read A | stage g=p+1 -> barrier -> setprio+16 MFMA -> barrier}.
// vmcnt never drained to 0 in the main loop.
// ---------------------------------------------------------------------------
template <bool CAT, int KTOT>
__global__ __launch_bounds__(512, 2)
void gemm256_k(const us16* __restrict__ Ap, long aSlice,
               const us16* __restrict__ A2p, long a2Slice,
               const us16* __restrict__ Btp, long bSlice,
               const float* __restrict__ bias,
               const float* __restrict__ dotW, float* __restrict__ partial)
{
  extern __shared__ us16 lds[];          // 65536 elems = 128 KiB
  const int tid = threadIdx.x;
  const int z = blockIdx.z;
  const int m0 = blockIdx.x * 256;
  const int n0 = blockIdx.y * 256;
  const int wv = tid >> 6, lane = tid & 63;
  const int wr = wv >> 2, wc = wv & 3;       // 2 x 4 wave grid
  const int wmBase = wr * 128, wnBase = wc * 64;
  const int fr = lane & 15, fk = (lane >> 4) * 8;
  const int rbase = (lane >> 4) * 4;

  // staging constants: group g covers rows g*64 + (tid>>3); chunk j = tid&7
  const int srow = tid >> 3;
  const int scol = ((tid & 7) ^ (srow & 7)) << 3;   // inverse-swizzled source col

  f32x4 acc[8][4];
#pragma unroll
  for (int i = 0; i < 8; i++)
#pragma unroll
    for (int j = 0; j < 4; j++) acc[i][j] = f32x4{0.f, 0.f, 0.f, 0.f};

  const us16* bb = Btp + (long)z * bSlice + (long)n0 * KTOT;

  auto stA = [&](int dbuf, int k0, int g) {
    const int r = g * 64 + srow;
    const us16* a;
    if constexpr (CAT) {
      a = (k0 < 512) ? Ap  + (long)z * aSlice  + (long)(m0 + r) * 512 + (k0 + scol)
                     : A2p + (long)z * a2Slice + (long)(m0 + r) * 512 + (k0 - 512 + scol);
    } else {
      a = Ap + (long)z * aSlice + (long)(m0 + r) * KTOT + (k0 + scol);
    }
    gload16(a, lds + dbuf * 32768 + g * 4096 + tid * 8);
  };
  auto stB = [&](int dbuf, int k0, int g) {
    const int r = g * 64 + srow;
    gload16(bb + (long)r * KTOT + (k0 + scol), lds + dbuf * 32768 + 16384 + g * 4096 + tid * 8);
  };

  constexpr int NT = KTOT / 64;
  // prologue: stage tile 0 (8 gloads/thread)
#pragma unroll
  for (int g = 0; g < 4; g++) { stA(0, 0, g); stB(0, 0, g); }

#pragma unroll 1
  for (int t = 0; t < NT; ++t) {
    const int d = t & 1;
    const us16* curA = lds + d * 32768;
    const us16* curB = lds + d * 32768 + 16384;
    const int kn = (t + 1) * 64;
    const bool more = (t + 1 < NT);

    if (more) {
      stA(d ^ 1, kn, 0); stB(d ^ 1, kn, 0);
      asm volatile("s_waitcnt vmcnt(2)" ::: "memory");   // tile t fully resident
    } else {
      asm volatile("s_waitcnt vmcnt(0)" ::: "memory");
    }
    __builtin_amdgcn_sched_barrier(0);
    __builtin_amdgcn_s_barrier();
    __builtin_amdgcn_sched_barrier(0);

    // B fragments for the whole K-tile (kept in regs across phases)
    bf16x8 bfg[4][2];
#pragma unroll
    for (int fb = 0; fb < 4; fb++)
#pragma unroll
      for (int ks = 0; ks < 2; ks++) {
        const int row = wnBase + fb * 16 + fr;
        bfg[fb][ks] = *(const bf16x8*)&curB[row * 64 + ((ks * 32 + fk) ^ ((row & 7) << 3))];
      }

#pragma unroll
    for (int p = 0; p < 4; p++) {
      bf16x8 af[2][2];
#pragma unroll
      for (int f = 0; f < 2; f++)
#pragma unroll
        for (int ks = 0; ks < 2; ks++) {
          const int row = wmBase + (2 * p + f) * 16 + fr;
          af[f][ks] = *(const bf16x8*)&curA[row * 64 + ((ks * 32 + fk) ^ ((row & 7) << 3))];
        }
      if (more && p < 3) { stA(d ^ 1, kn, p + 1); stB(d ^ 1, kn, p + 1); }
      __builtin_amdgcn_sched_barrier(0);
      __builtin_amdgcn_s_barrier();
      __builtin_amdgcn_s_setprio(1);
#pragma unroll
      for (int f = 0; f < 2; f++)
#pragma unroll
        for (int fn = 0; fn < 4; fn++)
#pragma unroll
          for (int ks = 0; ks < 2; ks++)
            acc[2 * p + f][fn] =
                __builtin_amdgcn_mfma_f32_16x16x32_bf16(af[f][ks], bfg[fn][ks], acc[2 * p + f][fn], 0, 0, 0);
      __builtin_amdgcn_s_setprio(0);
      __builtin_amdgcn_sched_barrier(0);
      __builtin_amdgcn_s_barrier();
      __builtin_amdgcn_sched_barrier(0);
    }
  }

  // EPI_DOT epilogue: hidden = lrelu(acc + bc1[col]); partial += hidden*W2[col]
  const float* bsl = bias + (long)z * 512;
  const float* wsl = dotW + (long)z * 512;
#pragma unroll
  for (int fm = 0; fm < 8; fm++) {
#pragma unroll
    for (int j = 0; j < 4; j++) {
      float p = 0.f;
#pragma unroll
      for (int fn = 0; fn < 4; fn++) {
        int col = n0 + wnBase + fn * 16 + fr;
        float v = acc[fm][fn][j] + bsl[col];
        v = lrelu(v);
        p += v * wsl[col];
      }
      p += __shfl_xor(p, 1); p += __shfl_xor(p, 2); p += __shfl_xor(p, 4); p += __shfl_xor(p, 8);
      if (fr == 0) {
        long row = (long)z * 8192 + (m0 + wmBase + fm * 16 + rbase + j);
        partial[row * 8 + blockIdx.y * 4 + wc] = p;
      }
    }
  }
}

// ---------------------------------------------------------------------------
// Attention (round-3 proven): per (b,e), 1 wave. KSV layout [b][n][384].
// ---------------------------------------------------------------------------
__global__ __launch_bounds__(256, 2)
void attn_k(const us16* __restrict__ ksv, us16* __restrict__ other, int e)
{
  __shared__ us16 t[4][8 * 392];
  const int wv = threadIdx.x >> 6, lane = threadIdx.x & 63;
  const long b = (long)blockIdx.x * 4 + wv;
  const us16* src = ksv + b * 3072;
#pragma unroll
  for (int i = 0; i < 6; i++) {
    int c = i * 64 + lane;
    int r = c / 48, cc = c - r * 48;
    *(int4*)&t[wv][r * 392 + cc * 8] = *(const int4*)&src[c * 8];
  }
  __syncthreads();
  const int i = lane >> 3, j = lane & 7;
  const us16* selp = &t[wv][i * 392 + 128];
  const us16* keyp = &t[wv][j * 392];
  float acc = 0.f;
#pragma unroll
  for (int d = 0; d < 128; d += 8) {
    u16x8 s8 = *(const u16x8*)&selp[d];
    u16x8 k8 = *(const u16x8*)&keyp[d];
#pragma unroll
    for (int q = 0; q < 8; q++) acc += bf2f(s8[q]) * bf2f(k8[q]);
  }
  acc *= 0.088388347648318447f;
  float mx = acc;
  mx = fmaxf(mx, __shfl_xor(mx, 1)); mx = fmaxf(mx, __shfl_xor(mx, 2)); mx = fmaxf(mx, __shfl_xor(mx, 4));
  float ex = __expf(acc - mx);
  float sm = ex;
  sm += __shfl_xor(sm, 1); sm += __shfl_xor(sm, 2); sm += __shfl_xor(sm, 4);
  float wsm = ex / sm;
  float wj[8];
  const int ibase = lane & 56;
#pragma unroll
  for (int jj = 0; jj < 8; jj++) wj[jj] = __shfl(wsm, ibase + jj);
  const int dbase = (lane & 7) * 16;
  float o[16];
#pragma unroll
  for (int q = 0; q < 16; q++) o[q] = 0.f;
#pragma unroll
  for (int jj = 0; jj < 8; jj++) {
    u16x8 v0 = *(const u16x8*)&t[wv][jj * 392 + 256 + dbase];
    u16x8 v1 = *(const u16x8*)&t[wv][jj * 392 + 256 + dbase + 8];
    float wgt = wj[jj];
#pragma unroll
    for (int q = 0; q < 8; q++) { o[q] += wgt * bf2f(v0[q]); o[8 + q] += wgt * bf2f(v1[q]); }
  }
  u16x8 r0, r1;
#pragma unroll
  for (int q = 0; q < 8; q++) { r0[q] = f2bf(o[q]); r1[q] = f2bf(o[8 + q]); }
  us16* dst = other + ((long)i * 8192 + b) * 512 + e * 128 + dbase;
  *(u16x8*)&dst[0] = r0;
  *(u16x8*)&dst[8] = r1;
}

// q[r] = b2[r>>13] + sum of 8 per-block partials
__global__ void reduce_dot_k(const float* __restrict__ part, const float* __restrict__ b2,
                             float* __restrict__ out)
{
  int r = blockIdx.x * 256 + threadIdx.x;
  const float4* p = (const float4*)(part + (long)r * 8);
  float4 a = p[0], b = p[1];
  out[r] = b2[r >> 13] + ((a.x + a.y) + (a.z + a.w)) + ((b.x + b.y) + (b.z + b.w));
}

// ---------------------------------------------------------------------------
extern "C" void kernel_launch(void* const* d_in, const int* in_sizes, int n_in,
                              void* d_out, int out_size, void* d_ws, size_t ws_size,
                              hipStream_t stream)
{
  const float* states = (const float*)d_in[0];
  const float* actions= (const float*)d_in[1];
  const float* Ws  = (const float*)d_in[2];
  const float* bs  = (const float*)d_in[3];
  const float* Wsa = (const float*)d_in[4];
  const float* bsa = (const float*)d_in[5];
  const float* Wk  = (const float*)d_in[6];
  const float* Wsel= (const float*)d_in[7];
  const float* Wv  = (const float*)d_in[8];
  const float* bv  = (const float*)d_in[9];
  const float* Wc1 = (const float*)d_in[10];
  const float* bc1 = (const float*)d_in[11];
  const float* Wc2 = (const float*)d_in[12];
  const float* bc2 = (const float*)d_in[13];
  const float* Wv1 = (const float*)d_in[14];
  const float* bv1 = (const float*)d_in[15];
  const float* Wv2 = (const float*)d_in[16];
  const float* bv2 = (const float*)d_in[17];

  char* ws = (char*)d_ws;
  constexpr size_t OFF_WST   = 0;
  constexpr size_t OFF_WSAT  = OFF_WST   + (size_t)8 * 512 * 64 * 2;
  constexpr size_t OFF_WKVST = OFF_WSAT  + (size_t)8 * 512 * 96 * 2;
  constexpr size_t OFF_WC1T  = OFF_WKVST + (size_t)4 * 384 * 512 * 2;
  constexpr size_t OFF_WV1T  = OFF_WC1T  + (size_t)8 * 512 * 1024 * 2;
  constexpr size_t OFF_ENC   = OFF_WV1T  + (size_t)8 * 512 * 1024 * 2;
  constexpr size_t OFF_OTHER = OFF_ENC   + (size_t)8 * 8192 * 512 * 2;
  constexpr size_t OFF_KSV   = OFF_OTHER + (size_t)8 * 8192 * 512 * 2;
  constexpr size_t OFF_PART  = OFF_KSV   + (size_t)8192 * 8 * 384 * 2;
  constexpr size_t NEED      = OFF_PART  + (size_t)65536 * 8 * 4;
  if (ws_size < NEED) return;

  us16* WST   = (us16*)(ws + OFF_WST);
  us16* WSAT  = (us16*)(ws + OFF_WSAT);
  us16* WKVST = (us16*)(ws + OFF_WKVST);
  us16* WC1T  = (us16*)(ws + OFF_WC1T);
  us16* WV1T  = (us16*)(ws + OFF_WV1T);
  us16* ENC   = (us16*)(ws + OFF_ENC);
  us16* OTHER = (us16*)(ws + OFF_OTHER);
  us16* KSV   = (us16*)(ws + OFF_KSV);
  float* PART = (float*)(ws + OFF_PART);

  // 128 KiB dynamic LDS opt-in for the 256^2 kernel; deterministic fallback.
  const bool big =
      hipFuncSetAttribute((const void*)gemm256_k<true, 1024>,
                          hipFuncAttributeMaxDynamicSharedMemorySize, 131072) == hipSuccess;

  dim3 tb(32, 8);
  tconv_k <<<dim3(2, 16, 8),  tb, 0, stream>>>(Ws,  (long)64 * 512, 64, 512, WST,  (long)512 * 64, 0, 64, 64);
  tconv_k <<<dim3(3, 16, 8),  tb, 0, stream>>>(Wsa, (long)80 * 512, 80, 512, WSAT, (long)512 * 96, 0, 96, 96);
  tconv3_k<<<dim3(16, 4, 12), tb, 0, stream>>>(Wk, Wsel, Wv, WKVST);
  tconvC_k<<<dim3(32, 16, 16),tb, 0, stream>>>(Wc1, Wv1, WC1T, WV1T);

  // sa_enc = lrelu([states|actions] @ Wsa + bsa)  -> ENC (bf16)
  enc_gemm_k<ASRC_F32_CAT, 96><<<dim3(64, 4, 8), 256, 0, stream>>>(
      states, (long)8192 * 64, actions, (long)8192 * 16, WSAT, (long)512 * 96, bsa, 512,
      ENC, (long)8192 * 512, 512);

  // per head: ksv = sa_enc @ [Wk|Wsel|Wv] (+bv,lrelu on vals), then attention
  for (int e = 0; e < 4; e++) {
    gemm64_k<false, EPI_KSV, 512><<<dim3(64, 3, 8), 256, 0, stream>>>(
        ENC, (long)8192 * 512, nullptr, 0, WKVST + (size_t)e * 384 * 512, 0, bv + e * 128,
        KSV, 384, 3072, nullptr, nullptr);
    attn_k<<<dim3(2048), 256, 0, stream>>>(KSV, OTHER, e);
  }

  // q = lrelu([sa_enc|other] @ Wc1 + bc1) @ Wc2 + bc2
  if (big) {
    gemm256_k<true, 1024><<<dim3(32, 2, 8), 512, 131072, stream>>>(
        ENC, (long)8192 * 512, OTHER, (long)8192 * 512, WC1T, (long)512 * 1024, bc1, Wc2, PART);
  } else {
    gemm64_k<true, EPI_DOT, 1024><<<dim3(64, 4, 8), 256, 0, stream>>>(
        ENC, (long)8192 * 512, OTHER, (long)8192 * 512, WC1T, (long)512 * 1024, bc1,
        nullptr, 0, 0, Wc2, PART);
  }
  reduce_dot_k<<<dim3(256), 256, 0, stream>>>(PART, bc2, (float*)d_out);

  // s_enc = lrelu(states @ Ws + bs) -> ENC (sa_enc is dead now)
  enc_gemm_k<ASRC_F32, 64><<<dim3(64, 4, 8), 256, 0, stream>>>(
      states, (long)8192 * 64, nullptr, 0, WST, (long)512 * 64, bs, 512,
      ENC, (long)8192 * 512, 512);

  // v = lrelu([s_enc|other] @ Wv1 + bv1) @ Wv2 + bv2
  if (big) {
    gemm256_k<true, 1024><<<dim3(32, 2, 8), 512, 131072, stream>>>(
        ENC, (long)8192 * 512, OTHER, (long)8192 * 512, WV1T, (long)512 * 1024, bv1, Wv2, PART);
  } else {
    gemm64_k<true, EPI_DOT, 1024><<<dim3(64, 4, 8), 256, 0, stream>>>(
        ENC, (long)8192 * 512, OTHER, (long)8192 * 512, WV1T, (long)512 * 1024, bv1,
        nullptr, 0, 0, Wv2, PART);
  }
  reduce_dot_k<<<dim3(256), 256, 0, stream>>>(PART, bv2, (float*)d_out + 65536);
}

// Round 8
// 428.969 us; speedup vs baseline: 1.0699x; 1.0273x over previous
//
#include <hip/hip_runtime.h>

// ---------------------------------------------------------------------------
// AttentionCritic on MI355X — round 8: gemm256 v2 (front-loaded staging so the
// per-tile vmcnt wait never lands on fresh loads), attn occupancy 2->4,
// merged final reduce. KSV/encoders = proven round-3 forms.
// ---------------------------------------------------------------------------

#define DEVI __device__ __forceinline__

typedef unsigned short us16;
typedef __bf16 bf16x8 __attribute__((ext_vector_type(8)));
typedef float f32x4 __attribute__((ext_vector_type(4)));
typedef unsigned short u16x8 __attribute__((ext_vector_type(8)));

DEVI us16 f2bf(float f) {
  unsigned u = __builtin_bit_cast(unsigned, f);
  u += 0x7FFFu + ((u >> 16) & 1u);          // round-to-nearest-even
  return (us16)(u >> 16);
}
DEVI float bf2f(us16 h) {
  unsigned u = ((unsigned)h) << 16;
  return __builtin_bit_cast(float, u);
}
DEVI float lrelu(float v) { return v > 0.f ? v : 0.01f * v; }
DEVI int pk2(float a, float b) { return (int)f2bf(a) | ((int)f2bf(b) << 16); }

// async global->LDS, 16B per lane. LDS dest must be linear: base + lane*16.
DEVI void gload16(const us16* g, us16* l) {
  __builtin_amdgcn_global_load_lds(
      (const __attribute__((address_space(1))) void*)g,
      (__attribute__((address_space(3))) void*)l, 16, 0, 0);
}

// ---------------------------------------------------------------------------
// Transpose + fp32->bf16 convert kernels
// ---------------------------------------------------------------------------
__global__ void tconv_k(const float* __restrict__ src, long srcSlice, int K, int O,
                        us16* __restrict__ dst, long dstSlice, int dstRowOff,
                        int ldd, int Kpad)
{
  __shared__ float t[32][33];
  const int s = blockIdx.z;
  const int k0 = blockIdx.x * 32, o0 = blockIdx.y * 32;
  const int lx = threadIdx.x, ly = threadIdx.y;
#pragma unroll
  for (int i = 0; i < 4; i++) {
    int k = k0 + ly + i * 8, o = o0 + lx;
    float v = 0.f;
    if (k < K && o < O) v = src[(long)s * srcSlice + (long)k * O + o];
    t[ly + i * 8][lx] = v;
  }
  __syncthreads();
#pragma unroll
  for (int i = 0; i < 4; i++) {
    int o = o0 + ly + i * 8, k = k0 + lx;
    if (o < O && k < Kpad)
      dst[(long)s * dstSlice + (long)(dstRowOff + o) * ldd + k] = f2bf(t[lx][ly + i * 8]);
  }
}

// Merged Wk/Wsel/Wv transpose -> WKVST[e][384][512]. grid (16,4,12), block (32,8).
__global__ void tconv3_k(const float* __restrict__ wk, const float* __restrict__ wsel,
                         const float* __restrict__ wv, us16* __restrict__ dst)
{
  __shared__ float t[32][33];
  const int zz = blockIdx.z;               // 0..11
  const int e = zz & 3, m = zz >> 2;       // m: 0=key 1=sel 2=val
  const float* src = ((m == 0) ? wk : (m == 1) ? wsel : wv) + (long)e * 512 * 128;
  us16* d = dst + (long)e * 384 * 512 + (long)(m * 128) * 512;
  const int k0 = blockIdx.x * 32, o0 = blockIdx.y * 32;
  const int lx = threadIdx.x, ly = threadIdx.y;
#pragma unroll
  for (int i = 0; i < 4; i++)
    t[ly + i * 8][lx] = src[(long)(k0 + ly + i * 8) * 128 + (o0 + lx)];
  __syncthreads();
#pragma unroll
  for (int i = 0; i < 4; i++)
    d[(long)(o0 + ly + i * 8) * 512 + (k0 + lx)] = f2bf(t[lx][ly + i * 8]);
}

// Merged Wc1/Wv1 transpose. grid (32,16,16), block (32,8).
__global__ void tconvC_k(const float* __restrict__ c1, const float* __restrict__ v1,
                         us16* __restrict__ dc, us16* __restrict__ dv)
{
  __shared__ float t[32][33];
  const int zz = blockIdx.z;               // 0..15
  const int n = zz & 7, m = zz >> 3;
  const float* src = ((m == 0) ? c1 : v1) + (long)n * 1024 * 512;
  us16* dst = ((m == 0) ? dc : dv) + (long)n * 512 * 1024;
  const int k0 = blockIdx.x * 32, o0 = blockIdx.y * 32;
  const int lx = threadIdx.x, ly = threadIdx.y;
#pragma unroll
  for (int i = 0; i < 4; i++)
    t[ly + i * 8][lx] = src[(long)(k0 + ly + i * 8) * 512 + (o0 + lx)];
  __syncthreads();
#pragma unroll
  for (int i = 0; i < 4; i++)
    dst[(long)(o0 + ly + i * 8) * 1024 + (k0 + lx)] = f2bf(t[lx][ly + i * 8]);
}

// ---------------------------------------------------------------------------
// fp32-input encoder GEMM (round-2/3 structure, BK=32, linear LDS). Proven.
// ---------------------------------------------------------------------------
enum { ASRC_F32 = 2, ASRC_F32_CAT = 3 };

template <int ASRC, int KTOT>
__global__ __launch_bounds__(256, 4)
void enc_gemm_k(const float* __restrict__ Ap, long aSlice,
                const float* __restrict__ A2p, long a2Slice,
                const us16* __restrict__ Btp, long bSlice,
                const float* __restrict__ bias, long biasSlice,
                us16* __restrict__ outB, long outSlice, long outRow)
{
  __shared__ us16 lA[128 * 32];
  __shared__ us16 lB[128 * 32];
  const int tid = threadIdx.x;
  const int z = blockIdx.z;
  const int m0 = blockIdx.x * 128;
  const int n0 = blockIdx.y * 128;
  const int wv = tid >> 6, lane = tid & 63;
  const int wm = (wv >> 1) * 64, wn = (wv & 1) * 64;
  const int fr = lane & 15, fk = (lane >> 4) * 8;
  const int rbase = (lane >> 4) * 4;
  const int grow = tid >> 2, gcol = (tid & 3) * 8;

  f32x4 acc[4][4];
#pragma unroll
  for (int i = 0; i < 4; i++)
#pragma unroll
    for (int j = 0; j < 4; j++) acc[i][j] = f32x4{0.f, 0.f, 0.f, 0.f};

  const us16* bbase = Btp + (long)z * bSlice + (long)n0 * KTOT;

  for (int k0 = 0; k0 < KTOT; k0 += 32) {
    int4 ra0, ra1;
    {
      const int srow = tid >> 1, scol0 = (tid & 1) * 16;
      const int kg = k0 + scol0;
      const float* a = nullptr;
      if constexpr (ASRC == ASRC_F32) {
        a = Ap + (long)z * aSlice + (long)(m0 + srow) * 64 + kg;
      } else {  // states(0..63) | actions(64..79) | zero pad(80..95)
        if (kg < 64)      a = Ap + (long)z * aSlice + (long)(m0 + srow) * 64 + kg;
        else if (kg < 80) a = A2p + (long)z * a2Slice + (long)(m0 + srow) * 16 + (kg - 64);
      }
      float4 f0, f1, f2, f3;
      if (a) { const float4* ap = (const float4*)a; f0 = ap[0]; f1 = ap[1]; f2 = ap[2]; f3 = ap[3]; }
      else   { f0 = make_float4(0.f, 0.f, 0.f, 0.f); f1 = f0; f2 = f0; f3 = f0; }
      ra0.x = pk2(f0.x, f0.y); ra0.y = pk2(f0.z, f0.w); ra0.z = pk2(f1.x, f1.y); ra0.w = pk2(f1.z, f1.w);
      ra1.x = pk2(f2.x, f2.y); ra1.y = pk2(f2.z, f2.w); ra1.z = pk2(f3.x, f3.y); ra1.w = pk2(f3.z, f3.w);
    }

    __syncthreads();
    {
      const us16* bb = bbase + k0 + gcol;
      gload16(bb + (long)grow * KTOT, &lB[tid * 8]);
      gload16(bb + (long)(64 + grow) * KTOT, &lB[2048 + tid * 8]);
    }
    {
      const int srow = tid >> 1, scol0 = (tid & 1) * 16;
      *(int4*)&lA[srow * 32 + scol0]     = ra0;
      *(int4*)&lA[srow * 32 + scol0 + 8] = ra1;
    }
    __syncthreads();

    bf16x8 af[4], bfg[4];
#pragma unroll
    for (int f = 0; f < 4; f++) af[f]  = *(const bf16x8*)&lA[(wm + f * 16 + fr) * 32 + fk];
#pragma unroll
    for (int f = 0; f < 4; f++) bfg[f] = *(const bf16x8*)&lB[(wn + f * 16 + fr) * 32 + fk];
#pragma unroll
    for (int fm = 0; fm < 4; fm++)
#pragma unroll
      for (int fn = 0; fn < 4; fn++)
        acc[fm][fn] = __builtin_amdgcn_mfma_f32_16x16x32_bf16(af[fm], bfg[fn], acc[fm][fn], 0, 0, 0);
  }

#pragma unroll
  for (int fm = 0; fm < 4; fm++) {
#pragma unroll
    for (int fn = 0; fn < 4; fn++) {
      int col = n0 + wn + fn * 16 + fr;
      float badd = bias[(long)z * biasSlice + col];
      us16* op = outB + (long)z * outSlice + (long)(m0 + wm + fm * 16 + rbase) * outRow + col;
#pragma unroll
      for (int j = 0; j < 4; j++) {
        float v = lrelu(acc[fm][fn][j] + badd);
        op[(long)j * outRow] = f2bf(v);
      }
    }
  }
}

// ---------------------------------------------------------------------------
// Round-3 proven 128^2 GEMM (BK=64, XOR-swizzle, 2-barrier). KSV + fallback.
// ---------------------------------------------------------------------------
enum { EPI_KSV = 1, EPI_DOT = 2 };

template <bool CAT, int EPI, int KTOT>
__global__ __launch_bounds__(256, 4)
void gemm64_k(const us16* __restrict__ Ap, long aSlice,
              const us16* __restrict__ A2p, long a2Slice,
              const us16* __restrict__ Btp, long bSlice,
              const float* __restrict__ bias,
              us16* __restrict__ outB, long outSlice, long outRow,
              const float* __restrict__ dotW, float* __restrict__ partial)
{
  __shared__ us16 lA[128 * 64];
  __shared__ us16 lB[128 * 64];
  const int tid = threadIdx.x;
  const int z = blockIdx.z;
  const int m0 = blockIdx.x * 128;
  const int n0 = blockIdx.y * 128;
  const int wv = tid >> 6, lane = tid & 63;
  const int wm = (wv >> 1) * 64, wn = (wv & 1) * 64;
  const int fr = lane & 15, fk = (lane >> 4) * 8;
  const int rbase = (lane >> 4) * 4;
  const int xorkey = (fr & 7) << 3;

  f32x4 acc[4][4];
#pragma unroll
  for (int i = 0; i < 4; i++)
#pragma unroll
    for (int j = 0; j < 4; j++) acc[i][j] = f32x4{0.f, 0.f, 0.f, 0.f};

  const us16* bbase = Btp + (long)z * bSlice + (long)n0 * KTOT;

  for (int k0 = 0; k0 < KTOT; k0 += 64) {
    __syncthreads();
#pragma unroll
    for (int i = 0; i < 4; i++) {
      const int c = i * 256 + tid;
      const int r = c >> 3;
      const int col = ((c & 7) ^ (r & 7)) << 3;
      const us16* a;
      if constexpr (!CAT) {
        a = Ap + (long)z * aSlice + (long)(m0 + r) * KTOT + (k0 + col);
      } else {
        const int kg = k0 + col;
        a = (kg < 512) ? Ap  + (long)z * aSlice  + (long)(m0 + r) * 512 + kg
                       : A2p + (long)z * a2Slice + (long)(m0 + r) * 512 + (kg - 512);
      }
      gload16(a, &lA[c * 8]);
    }
#pragma unroll
    for (int i = 0; i < 4; i++) {
      const int c = i * 256 + tid;
      const int r = c >> 3;
      const int col = ((c & 7) ^ (r & 7)) << 3;
      gload16(bbase + (long)r * KTOT + (k0 + col), &lB[c * 8]);
    }
    __syncthreads();

#pragma unroll
    for (int ks = 0; ks < 2; ks++) {
      bf16x8 af[4], bfg[4];
      const int kc = ks * 32 + fk;
#pragma unroll
      for (int f = 0; f < 4; f++)
        af[f]  = *(const bf16x8*)&lA[(wm + f * 16 + fr) * 64 + (kc ^ xorkey)];
#pragma unroll
      for (int f = 0; f < 4; f++)
        bfg[f] = *(const bf16x8*)&lB[(wn + f * 16 + fr) * 64 + (kc ^ xorkey)];
#pragma unroll
      for (int fm = 0; fm < 4; fm++)
#pragma unroll
        for (int fn = 0; fn < 4; fn++)
          acc[fm][fn] = __builtin_amdgcn_mfma_f32_16x16x32_bf16(af[fm], bfg[fn], acc[fm][fn], 0, 0, 0);
    }
  }

  if constexpr (EPI == EPI_DOT) {
    const float* bsl = bias + (long)z * 512;
    const float* wsl = dotW + (long)z * 512;
#pragma unroll
    for (int fm = 0; fm < 4; fm++) {
#pragma unroll
      for (int j = 0; j < 4; j++) {
        float p = 0.f;
#pragma unroll
        for (int fn = 0; fn < 4; fn++) {
          int col = n0 + wn + fn * 16 + fr;
          float v = acc[fm][fn][j] + bsl[col];
          v = lrelu(v);
          p += v * wsl[col];
        }
        p += __shfl_xor(p, 1); p += __shfl_xor(p, 2); p += __shfl_xor(p, 4); p += __shfl_xor(p, 8);
        if (fr == 0) {
          long row = (long)z * 8192 + (m0 + wm + fm * 16 + rbase + j);
          partial[row * 8 + blockIdx.y * 2 + (wv & 1)] = p;
        }
      }
    }
  } else {
#pragma unroll
    for (int fm = 0; fm < 4; fm++) {
#pragma unroll
      for (int fn = 0; fn < 4; fn++) {
        int col = n0 + wn + fn * 16 + fr;
        float badd = 0.f; bool act = false;
        if (col >= 256) { badd = bias[col - 256]; act = true; }
        us16* op = outB + (long)z * outSlice + (long)(m0 + wm + fm * 16 + rbase) * outRow + col;
#pragma unroll
        for (int j = 0; j < 4; j++) {
          float v = acc[fm][fn][j] + badd;
          if (act) v = lrelu(v);
          op[(long)j * outRow] = f2bf(v);
        }
      }
    }
  }
}

// ---------------------------------------------------------------------------
// 256^2 8-wave GEMM v2: staging of tile t+1 is FRONT-LOADED into phases 0-1
// (4 gloads/thread each), so the per-tile vmcnt(0) wait only ever sees loads
// issued >= 2.5 phases earlier (stall ~ 0). 128 KiB dyn LDS, 2 buffers.
// ---------------------------------------------------------------------------
template <bool CAT, int KTOT>
__global__ __launch_bounds__(512, 2)
void gemm256_k(const us16* __restrict__ Ap, long aSlice,
               const us16* __restrict__ A2p, long a2Slice,
               const us16* __restrict__ Btp, long bSlice,
               const float* __restrict__ bias,
               const float* __restrict__ dotW, float* __restrict__ partial)
{
  extern __shared__ us16 lds[];          // 65536 elems = 128 KiB
  const int tid = threadIdx.x;
  const int z = blockIdx.z;
  const int m0 = blockIdx.x * 256;
  const int n0 = blockIdx.y * 256;
  const int wv = tid >> 6, lane = tid & 63;
  const int wr = wv >> 2, wc = wv & 3;       // 2 x 4 wave grid
  const int wmBase = wr * 128, wnBase = wc * 64;
  const int fr = lane & 15, fk = (lane >> 4) * 8;
  const int rbase = (lane >> 4) * 4;

  const int srow = tid >> 3;                        // 0..63
  const int scol = ((tid & 7) ^ (srow & 7)) << 3;   // inverse-swizzled source col

  f32x4 acc[8][4];
#pragma unroll
  for (int i = 0; i < 8; i++)
#pragma unroll
    for (int j = 0; j < 4; j++) acc[i][j] = f32x4{0.f, 0.f, 0.f, 0.f};

  const us16* bb = Btp + (long)z * bSlice + (long)n0 * KTOT;

  auto stA = [&](int dbuf, int k0, int g) {
    const int r = g * 64 + srow;
    const us16* a;
    if constexpr (CAT) {
      a = (k0 < 512) ? Ap  + (long)z * aSlice  + (long)(m0 + r) * 512 + (k0 + scol)
                     : A2p + (long)z * a2Slice + (long)(m0 + r) * 512 + (k0 - 512 + scol);
    } else {
      a = Ap + (long)z * aSlice + (long)(m0 + r) * KTOT + (k0 + scol);
    }
    gload16(a, lds + dbuf * 32768 + g * 4096 + tid * 8);
  };
  auto stB = [&](int dbuf, int k0, int g) {
    const int r = g * 64 + srow;
    gload16(bb + (long)r * KTOT + (k0 + scol), lds + dbuf * 32768 + 16384 + g * 4096 + tid * 8);
  };

  constexpr int NT = KTOT / 64;
  // prologue: stage tile 0 (8 gloads/thread)
#pragma unroll
  for (int g = 0; g < 4; g++) { stA(0, 0, g); stB(0, 0, g); }

#pragma unroll 1
  for (int t = 0; t < NT; ++t) {
    const int d = t & 1;
    const us16* curA = lds + d * 32768;
    const us16* curB = lds + d * 32768 + 16384;
    const int kn = (t + 1) * 64;
    const bool more = (t + 1 < NT);

    // tile t resident: every outstanding load is >= 2.5 phases old
    asm volatile("s_waitcnt vmcnt(0)" ::: "memory");
    __builtin_amdgcn_sched_barrier(0);
    __builtin_amdgcn_s_barrier();
    __builtin_amdgcn_sched_barrier(0);

    // B fragments for the whole K-tile (kept in regs across phases)
    bf16x8 bfg[4][2];
#pragma unroll
    for (int fb = 0; fb < 4; fb++)
#pragma unroll
      for (int ks = 0; ks < 2; ks++) {
        const int row = wnBase + fb * 16 + fr;
        bfg[fb][ks] = *(const bf16x8*)&curB[row * 64 + ((ks * 32 + fk) ^ ((row & 7) << 3))];
      }

#pragma unroll
    for (int p = 0; p < 4; p++) {
      bf16x8 af[2][2];
#pragma unroll
      for (int f = 0; f < 2; f++)
#pragma unroll
        for (int ks = 0; ks < 2; ks++) {
          const int row = wmBase + (2 * p + f) * 16 + fr;
          af[f][ks] = *(const bf16x8*)&curA[row * 64 + ((ks * 32 + fk) ^ ((row & 7) << 3))];
        }
      // front-loaded staging: all 8 loads of tile t+1 issued in phases 0-1
      if (more && p == 0) { stA(d ^ 1, kn, 0); stA(d ^ 1, kn, 1); stB(d ^ 1, kn, 0); stB(d ^ 1, kn, 1); }
      if (more && p == 1) { stA(d ^ 1, kn, 2); stA(d ^ 1, kn, 3); stB(d ^ 1, kn, 2); stB(d ^ 1, kn, 3); }
      __builtin_amdgcn_sched_barrier(0);
      __builtin_amdgcn_s_barrier();
      __builtin_amdgcn_s_setprio(1);
#pragma unroll
      for (int f = 0; f < 2; f++)
#pragma unroll
        for (int fn = 0; fn < 4; fn++)
#pragma unroll
          for (int ks = 0; ks < 2; ks++)
            acc[2 * p + f][fn] =
                __builtin_amdgcn_mfma_f32_16x16x32_bf16(af[f][ks], bfg[fn][ks], acc[2 * p + f][fn], 0, 0, 0);
      __builtin_amdgcn_s_setprio(0);
      __builtin_amdgcn_sched_barrier(0);
      __builtin_amdgcn_s_barrier();
      __builtin_amdgcn_sched_barrier(0);
    }
  }

  // EPI_DOT epilogue: hidden = lrelu(acc + b1[col]); partial += hidden*W2[col]
  const float* bsl = bias + (long)z * 512;
  const float* wsl = dotW + (long)z * 512;
#pragma unroll
  for (int fm = 0; fm < 8; fm++) {
#pragma unroll
    for (int j = 0; j < 4; j++) {
      float p = 0.f;
#pragma unroll
      for (int fn = 0; fn < 4; fn++) {
        int col = n0 + wnBase + fn * 16 + fr;
        float v = acc[fm][fn][j] + bsl[col];
        v = lrelu(v);
        p += v * wsl[col];
      }
      p += __shfl_xor(p, 1); p += __shfl_xor(p, 2); p += __shfl_xor(p, 4); p += __shfl_xor(p, 8);
      if (fr == 0) {
        long row = (long)z * 8192 + (m0 + wmBase + fm * 16 + rbase + j);
        partial[row * 8 + blockIdx.y * 4 + wc] = p;
      }
    }
  }
}

// ---------------------------------------------------------------------------
// Attention: per (b,e), 1 wave. KSV layout [b][n][384]. Occupancy 4 blocks/CU.
// ---------------------------------------------------------------------------
__global__ __launch_bounds__(256, 4)
void attn_k(const us16* __restrict__ ksv, us16* __restrict__ other, int e)
{
  __shared__ us16 t[4][8 * 392];
  const int wv = threadIdx.x >> 6, lane = threadIdx.x & 63;
  const long b = (long)blockIdx.x * 4 + wv;
  const us16* src = ksv + b * 3072;
#pragma unroll
  for (int i = 0; i < 6; i++) {
    int c = i * 64 + lane;
    int r = c / 48, cc = c - r * 48;
    *(int4*)&t[wv][r * 392 + cc * 8] = *(const int4*)&src[c * 8];
  }
  __syncthreads();
  const int i = lane >> 3, j = lane & 7;
  const us16* selp = &t[wv][i * 392 + 128];
  const us16* keyp = &t[wv][j * 392];
  float acc = 0.f;
#pragma unroll
  for (int d = 0; d < 128; d += 8) {
    u16x8 s8 = *(const u16x8*)&selp[d];
    u16x8 k8 = *(const u16x8*)&keyp[d];
#pragma unroll
    for (int q = 0; q < 8; q++) acc += bf2f(s8[q]) * bf2f(k8[q]);
  }
  acc *= 0.088388347648318447f;
  float mx = acc;
  mx = fmaxf(mx, __shfl_xor(mx, 1)); mx = fmaxf(mx, __shfl_xor(mx, 2)); mx = fmaxf(mx, __shfl_xor(mx, 4));
  float ex = __expf(acc - mx);
  float sm = ex;
  sm += __shfl_xor(sm, 1); sm += __shfl_xor(sm, 2); sm += __shfl_xor(sm, 4);
  float wsm = ex / sm;
  float wj[8];
  const int ibase = lane & 56;
#pragma unroll
  for (int jj = 0; jj < 8; jj++) wj[jj] = __shfl(wsm, ibase + jj);
  const int dbase = (lane & 7) * 16;
  float o[16];
#pragma unroll
  for (int q = 0; q < 16; q++) o[q] = 0.f;
#pragma unroll
  for (int jj = 0; jj < 8; jj++) {
    u16x8 v0 = *(const u16x8*)&t[wv][jj * 392 + 256 + dbase];
    u16x8 v1 = *(const u16x8*)&t[wv][jj * 392 + 256 + dbase + 8];
    float wgt = wj[jj];
#pragma unroll
    for (int q = 0; q < 8; q++) { o[q] += wgt * bf2f(v0[q]); o[8 + q] += wgt * bf2f(v1[q]); }
  }
  u16x8 r0, r1;
#pragma unroll
  for (int q = 0; q < 8; q++) { r0[q] = f2bf(o[q]); r1[q] = f2bf(o[8 + q]); }
  us16* dst = other + ((long)i * 8192 + b) * 512 + e * 128 + dbase;
  *(u16x8*)&dst[0] = r0;
  *(u16x8*)&dst[8] = r1;
}

// merged final reduce: r < 65536 -> q (bc2), else v (bv2). grid 512 x 256.
__global__ void reduce2_k(const float* __restrict__ part, const float* __restrict__ b2c,
                          const float* __restrict__ b2v, float* __restrict__ out)
{
  int r = blockIdx.x * 256 + threadIdx.x;   // 0..131071
  const float4* p = (const float4*)(part + (long)r * 8);
  float4 a = p[0], b = p[1];
  float s = ((a.x + a.y) + (a.z + a.w)) + ((b.x + b.y) + (b.z + b.w));
  int agent = (r >> 13) & 7;
  out[r] = s + ((r < 65536) ? b2c[agent] : b2v[agent]);
}

// ---------------------------------------------------------------------------
extern "C" void kernel_launch(void* const* d_in, const int* in_sizes, int n_in,
                              void* d_out, int out_size, void* d_ws, size_t ws_size,
                              hipStream_t stream)
{
  const float* states = (const float*)d_in[0];
  const float* actions= (const float*)d_in[1];
  const float* Ws  = (const float*)d_in[2];
  const float* bs  = (const float*)d_in[3];
  const float* Wsa = (const float*)d_in[4];
  const float* bsa = (const float*)d_in[5];
  const float* Wk  = (const float*)d_in[6];
  const float* Wsel= (const float*)d_in[7];
  const float* Wv  = (const float*)d_in[8];
  const float* bv  = (const float*)d_in[9];
  const float* Wc1 = (const float*)d_in[10];
  const float* bc1 = (const float*)d_in[11];
  const float* Wc2 = (const float*)d_in[12];
  const float* bc2 = (const float*)d_in[13];
  const float* Wv1 = (const float*)d_in[14];
  const float* bv1 = (const float*)d_in[15];
  const float* Wv2 = (const float*)d_in[16];
  const float* bv2 = (const float*)d_in[17];

  char* ws = (char*)d_ws;
  constexpr size_t OFF_WST   = 0;
  constexpr size_t OFF_WSAT  = OFF_WST   + (size_t)8 * 512 * 64 * 2;
  constexpr size_t OFF_WKVST = OFF_WSAT  + (size_t)8 * 512 * 96 * 2;
  constexpr size_t OFF_WC1T  = OFF_WKVST + (size_t)4 * 384 * 512 * 2;
  constexpr size_t OFF_WV1T  = OFF_WC1T  + (size_t)8 * 512 * 1024 * 2;
  constexpr size_t OFF_ENC   = OFF_WV1T  + (size_t)8 * 512 * 1024 * 2;
  constexpr size_t OFF_OTHER = OFF_ENC   + (size_t)8 * 8192 * 512 * 2;
  constexpr size_t OFF_KSV   = OFF_OTHER + (size_t)8 * 8192 * 512 * 2;
  constexpr size_t OFF_PART  = OFF_KSV   + (size_t)8192 * 8 * 384 * 2;
  constexpr size_t NEED      = OFF_PART  + (size_t)131072 * 8 * 4;
  if (ws_size < NEED) return;

  us16* WST   = (us16*)(ws + OFF_WST);
  us16* WSAT  = (us16*)(ws + OFF_WSAT);
  us16* WKVST = (us16*)(ws + OFF_WKVST);
  us16* WC1T  = (us16*)(ws + OFF_WC1T);
  us16* WV1T  = (us16*)(ws + OFF_WV1T);
  us16* ENC   = (us16*)(ws + OFF_ENC);
  us16* OTHER = (us16*)(ws + OFF_OTHER);
  us16* KSV   = (us16*)(ws + OFF_KSV);
  float* PART = (float*)(ws + OFF_PART);     // [131072][8]: critic rows 0..65535, value 65536..

  // 128 KiB dynamic LDS opt-in for the 256^2 kernel; deterministic fallback.
  const bool big =
      hipFuncSetAttribute((const void*)gemm256_k<true, 1024>,
                          hipFuncAttributeMaxDynamicSharedMemorySize, 131072) == hipSuccess;

  dim3 tb(32, 8);
  tconv_k <<<dim3(2, 16, 8),  tb, 0, stream>>>(Ws,  (long)64 * 512, 64, 512, WST,  (long)512 * 64, 0, 64, 64);
  tconv_k <<<dim3(3, 16, 8),  tb, 0, stream>>>(Wsa, (long)80 * 512, 80, 512, WSAT, (long)512 * 96, 0, 96, 96);
  tconv3_k<<<dim3(16, 4, 12), tb, 0, stream>>>(Wk, Wsel, Wv, WKVST);
  tconvC_k<<<dim3(32, 16, 16),tb, 0, stream>>>(Wc1, Wv1, WC1T, WV1T);

  // sa_enc = lrelu([states|actions] @ Wsa + bsa)  -> ENC (bf16)
  enc_gemm_k<ASRC_F32_CAT, 96><<<dim3(64, 4, 8), 256, 0, stream>>>(
      states, (long)8192 * 64, actions, (long)8192 * 16, WSAT, (long)512 * 96, bsa, 512,
      ENC, (long)8192 * 512, 512);

  // per head: ksv = sa_enc @ [Wk|Wsel|Wv] (+bv,lrelu on vals), then attention
  for (int e = 0; e < 4; e++) {
    gemm64_k<false, EPI_KSV, 512><<<dim3(64, 3, 8), 256, 0, stream>>>(
        ENC, (long)8192 * 512, nullptr, 0, WKVST + (size_t)e * 384 * 512, 0, bv + e * 128,
        KSV, 384, 3072, nullptr, nullptr);
    attn_k<<<dim3(2048), 256, 0, stream>>>(KSV, OTHER, e);
  }

  // q = lrelu([sa_enc|other] @ Wc1 + bc1) @ Wc2 + bc2  -> PART rows 0..65535
  if (big) {
    gemm256_k<true, 1024><<<dim3(32, 2, 8), 512, 131072, stream>>>(
        ENC, (long)8192 * 512, OTHER, (long)8192 * 512, WC1T, (long)512 * 1024, bc1, Wc2, PART);
  } else {
    gemm64_k<true, EPI_DOT, 1024><<<dim3(64, 4, 8), 256, 0, stream>>>(
        ENC, (long)8192 * 512, OTHER, (long)8192 * 512, WC1T, (long)512 * 1024, bc1,
        nullptr, 0, 0, Wc2, PART);
  }

  // s_enc = lrelu(states @ Ws + bs) -> ENC (sa_enc is dead now)
  enc_gemm_k<ASRC_F32, 64><<<dim3(64, 4, 8), 256, 0, stream>>>(
      states, (long)8192 * 64, nullptr, 0, WST, (long)512 * 64, bs, 512,
      ENC, (long)8192 * 512, 512);

  // v = lrelu([s_enc|other] @ Wv1 + bv1) @ Wv2 + bv2  -> PART rows 65536..131071
  if (big) {
    gemm256_k<true, 1024><<<dim3(32, 2, 8), 512, 131072, stream>>>(
        ENC, (long)8192 * 512, OTHER, (long)8192 * 512, WV1T, (long)512 * 1024, bv1, Wv2,
        PART + (size_t)65536 * 8);
  } else {
    gemm64_k<true, EPI_DOT, 1024><<<dim3(64, 4, 8), 256, 0, stream>>>(
        ENC, (long)8192 * 512, OTHER, (long)8192 * 512, WV1T, (long)512 * 1024, bv1,
        nullptr, 0, 0, Wv2, PART + (size_t)65536 * 8);
  }

  // merged final reduce: writes q then v into d_out
  reduce2_k<<<dim3(512), 256, 0, stream>>>(PART, bc2, bv2, (float*)d_out);
}

// Round 9
// 417.692 us; speedup vs baseline: 1.0988x; 1.0270x over previous
//
#include <hip/hip_runtime.h>

// ---------------------------------------------------------------------------
// AttentionCritic on MI355X — round 9: gemm64 everywhere (measured best),
// dispatch fusion: tiered on ws_size. Tier A (big ws): KSV×4 -> 1, attn×4 -> 1,
// both MLP DOTs -> 1 (needs ENC2 + KSV4 buffers). Tier B: round-8 structure.
// ---------------------------------------------------------------------------

#define DEVI __device__ __forceinline__

typedef unsigned short us16;
typedef __bf16 bf16x8 __attribute__((ext_vector_type(8)));
typedef float f32x4 __attribute__((ext_vector_type(4)));
typedef unsigned short u16x8 __attribute__((ext_vector_type(8)));

DEVI us16 f2bf(float f) {
  unsigned u = __builtin_bit_cast(unsigned, f);
  u += 0x7FFFu + ((u >> 16) & 1u);          // round-to-nearest-even
  return (us16)(u >> 16);
}
DEVI float bf2f(us16 h) {
  unsigned u = ((unsigned)h) << 16;
  return __builtin_bit_cast(float, u);
}
DEVI float lrelu(float v) { return v > 0.f ? v : 0.01f * v; }
DEVI int pk2(float a, float b) { return (int)f2bf(a) | ((int)f2bf(b) << 16); }

// async global->LDS, 16B per lane. LDS dest must be linear: base + lane*16.
DEVI void gload16(const us16* g, us16* l) {
  __builtin_amdgcn_global_load_lds(
      (const __attribute__((address_space(1))) void*)g,
      (__attribute__((address_space(3))) void*)l, 16, 0, 0);
}

// ---------------------------------------------------------------------------
// Transposes (fp32 -> bf16, [K][O] -> [O][Kpad])
// ---------------------------------------------------------------------------
// Merged Ws + Wsa transpose. grid (3,16,16), block (32,8). z<8: Ws, else Wsa.
__global__ void tconvSA_k(const float* __restrict__ wsrc, const float* __restrict__ wsasrc,
                          us16* __restrict__ wst, us16* __restrict__ wsat)
{
  __shared__ float t[32][33];
  const int zz = blockIdx.z;               // 0..15
  const int m = zz >> 3, s = zz & 7;
  const int K = m ? 80 : 64, Kpad = m ? 96 : 64;
  const float* src = m ? (wsasrc + (long)s * 80 * 512) : (wsrc + (long)s * 64 * 512);
  us16* dst = m ? (wsat + (long)s * 512 * 96) : (wst + (long)s * 512 * 64);
  const int k0 = blockIdx.x * 32, o0 = blockIdx.y * 32;
  const int lx = threadIdx.x, ly = threadIdx.y;
#pragma unroll
  for (int i = 0; i < 4; i++) {
    int k = k0 + ly + i * 8, o = o0 + lx;
    float v = 0.f;
    if (k < K) v = src[(long)k * 512 + o];
    t[ly + i * 8][lx] = v;
  }
  __syncthreads();
#pragma unroll
  for (int i = 0; i < 4; i++) {
    int o = o0 + ly + i * 8, k = k0 + lx;
    if (k < Kpad)
      dst[(long)o * Kpad + k] = f2bf(t[lx][ly + i * 8]);
  }
}

// Merged Wk/Wsel/Wv transpose -> WKVST[e][384][512]. grid (16,4,12), block (32,8).
__global__ void tconv3_k(const float* __restrict__ wk, const float* __restrict__ wsel,
                         const float* __restrict__ wv, us16* __restrict__ dst)
{
  __shared__ float t[32][33];
  const int zz = blockIdx.z;               // 0..11
  const int e = zz & 3, m = zz >> 2;       // m: 0=key 1=sel 2=val
  const float* src = ((m == 0) ? wk : (m == 1) ? wsel : wv) + (long)e * 512 * 128;
  us16* d = dst + (long)e * 384 * 512 + (long)(m * 128) * 512;
  const int k0 = blockIdx.x * 32, o0 = blockIdx.y * 32;
  const int lx = threadIdx.x, ly = threadIdx.y;
#pragma unroll
  for (int i = 0; i < 4; i++)
    t[ly + i * 8][lx] = src[(long)(k0 + ly + i * 8) * 128 + (o0 + lx)];
  __syncthreads();
#pragma unroll
  for (int i = 0; i < 4; i++)
    d[(long)(o0 + ly + i * 8) * 512 + (k0 + lx)] = f2bf(t[lx][ly + i * 8]);
}

// Merged Wc1/Wv1 transpose. grid (32,16,16), block (32,8).
__global__ void tconvC_k(const float* __restrict__ c1, const float* __restrict__ v1,
                         us16* __restrict__ dc, us16* __restrict__ dv)
{
  __shared__ float t[32][33];
  const int zz = blockIdx.z;               // 0..15
  const int n = zz & 7, m = zz >> 3;
  const float* src = ((m == 0) ? c1 : v1) + (long)n * 1024 * 512;
  us16* dst = ((m == 0) ? dc : dv) + (long)n * 512 * 1024;
  const int k0 = blockIdx.x * 32, o0 = blockIdx.y * 32;
  const int lx = threadIdx.x, ly = threadIdx.y;
#pragma unroll
  for (int i = 0; i < 4; i++)
    t[ly + i * 8][lx] = src[(long)(k0 + ly + i * 8) * 512 + (o0 + lx)];
  __syncthreads();
#pragma unroll
  for (int i = 0; i < 4; i++)
    dst[(long)(o0 + ly + i * 8) * 1024 + (k0 + lx)] = f2bf(t[lx][ly + i * 8]);
}

// ---------------------------------------------------------------------------
// fp32-input encoder GEMM (proven, BK=32, linear LDS).
// ---------------------------------------------------------------------------
enum { ASRC_F32 = 2, ASRC_F32_CAT = 3 };

template <int ASRC, int KTOT>
__global__ __launch_bounds__(256, 4)
void enc_gemm_k(const float* __restrict__ Ap, long aSlice,
                const float* __restrict__ A2p, long a2Slice,
                const us16* __restrict__ Btp, long bSlice,
                const float* __restrict__ bias, long biasSlice,
                us16* __restrict__ outB, long outSlice, long outRow)
{
  __shared__ us16 lA[128 * 32];
  __shared__ us16 lB[128 * 32];
  const int tid = threadIdx.x;
  const int z = blockIdx.z;
  const int m0 = blockIdx.x * 128;
  const int n0 = blockIdx.y * 128;
  const int wv = tid >> 6, lane = tid & 63;
  const int wm = (wv >> 1) * 64, wn = (wv & 1) * 64;
  const int fr = lane & 15, fk = (lane >> 4) * 8;
  const int rbase = (lane >> 4) * 4;
  const int grow = tid >> 2, gcol = (tid & 3) * 8;

  f32x4 acc[4][4];
#pragma unroll
  for (int i = 0; i < 4; i++)
#pragma unroll
    for (int j = 0; j < 4; j++) acc[i][j] = f32x4{0.f, 0.f, 0.f, 0.f};

  const us16* bbase = Btp + (long)z * bSlice + (long)n0 * KTOT;

  for (int k0 = 0; k0 < KTOT; k0 += 32) {
    int4 ra0, ra1;
    {
      const int srow = tid >> 1, scol0 = (tid & 1) * 16;
      const int kg = k0 + scol0;
      const float* a = nullptr;
      if constexpr (ASRC == ASRC_F32) {
        a = Ap + (long)z * aSlice + (long)(m0 + srow) * 64 + kg;
      } else {  // states(0..63) | actions(64..79) | zero pad(80..95)
        if (kg < 64)      a = Ap + (long)z * aSlice + (long)(m0 + srow) * 64 + kg;
        else if (kg < 80) a = A2p + (long)z * a2Slice + (long)(m0 + srow) * 16 + (kg - 64);
      }
      float4 f0, f1, f2, f3;
      if (a) { const float4* ap = (const float4*)a; f0 = ap[0]; f1 = ap[1]; f2 = ap[2]; f3 = ap[3]; }
      else   { f0 = make_float4(0.f, 0.f, 0.f, 0.f); f1 = f0; f2 = f0; f3 = f0; }
      ra0.x = pk2(f0.x, f0.y); ra0.y = pk2(f0.z, f0.w); ra0.z = pk2(f1.x, f1.y); ra0.w = pk2(f1.z, f1.w);
      ra1.x = pk2(f2.x, f2.y); ra1.y = pk2(f2.z, f2.w); ra1.z = pk2(f3.x, f3.y); ra1.w = pk2(f3.z, f3.w);
    }

    __syncthreads();
    {
      const us16* bb = bbase + k0 + gcol;
      gload16(bb + (long)grow * KTOT, &lB[tid * 8]);
      gload16(bb + (long)(64 + grow) * KTOT, &lB[2048 + tid * 8]);
    }
    {
      const int srow = tid >> 1, scol0 = (tid & 1) * 16;
      *(int4*)&lA[srow * 32 + scol0]     = ra0;
      *(int4*)&lA[srow * 32 + scol0 + 8] = ra1;
    }
    __syncthreads();

    bf16x8 af[4], bfg[4];
#pragma unroll
    for (int f = 0; f < 4; f++) af[f]  = *(const bf16x8*)&lA[(wm + f * 16 + fr) * 32 + fk];
#pragma unroll
    for (int f = 0; f < 4; f++) bfg[f] = *(const bf16x8*)&lB[(wn + f * 16 + fr) * 32 + fk];
#pragma unroll
    for (int fm = 0; fm < 4; fm++)
#pragma unroll
      for (int fn = 0; fn < 4; fn++)
        acc[fm][fn] = __builtin_amdgcn_mfma_f32_16x16x32_bf16(af[fm], bfg[fn], acc[fm][fn], 0, 0, 0);
  }

#pragma unroll
  for (int fm = 0; fm < 4; fm++) {
#pragma unroll
    for (int fn = 0; fn < 4; fn++) {
      int col = n0 + wn + fn * 16 + fr;
      float badd = bias[(long)z * biasSlice + col];
      us16* op = outB + (long)z * outSlice + (long)(m0 + wm + fm * 16 + rbase) * outRow + col;
#pragma unroll
      for (int j = 0; j < 4; j++) {
        float v = lrelu(acc[fm][fn][j] + badd);
        op[(long)j * outRow] = f2bf(v);
      }
    }
  }
}

// ---------------------------------------------------------------------------
// Proven 128^2 bf16 GEMM body pieces (BK=64, XOR-swizzle, 2-barrier).
// ---------------------------------------------------------------------------
enum { EPI_KSV = 1, EPI_DOT = 2 };

template <bool CAT, int EPI, int KTOT>
__global__ __launch_bounds__(256, 4)
void gemm64_k(const us16* __restrict__ Ap, long aSlice,
              const us16* __restrict__ A2p, long a2Slice,
              const us16* __restrict__ Btp, long bSlice,
              const float* __restrict__ bias,
              us16* __restrict__ outB, long outSlice, long outRow,
              const float* __restrict__ dotW, float* __restrict__ partial)
{
  __shared__ us16 lA[128 * 64];
  __shared__ us16 lB[128 * 64];
  const int tid = threadIdx.x;
  const int z = blockIdx.z;
  const int m0 = blockIdx.x * 128;
  const int n0 = blockIdx.y * 128;
  const int wv = tid >> 6, lane = tid & 63;
  const int wm = (wv >> 1) * 64, wn = (wv & 1) * 64;
  const int fr = lane & 15, fk = (lane >> 4) * 8;
  const int rbase = (lane >> 4) * 4;
  const int xorkey = (fr & 7) << 3;

  f32x4 acc[4][4];
#pragma unroll
  for (int i = 0; i < 4; i++)
#pragma unroll
    for (int j = 0; j < 4; j++) acc[i][j] = f32x4{0.f, 0.f, 0.f, 0.f};

  const us16* bbase = Btp + (long)z * bSlice + (long)n0 * KTOT;

  for (int k0 = 0; k0 < KTOT; k0 += 64) {
    __syncthreads();
#pragma unroll
    for (int i = 0; i < 4; i++) {
      const int c = i * 256 + tid;
      const int r = c >> 3;
      const int col = ((c & 7) ^ (r & 7)) << 3;
      const us16* a;
      if constexpr (!CAT) {
        a = Ap + (long)z * aSlice + (long)(m0 + r) * KTOT + (k0 + col);
      } else {
        const int kg = k0 + col;
        a = (kg < 512) ? Ap  + (long)z * aSlice  + (long)(m0 + r) * 512 + kg
                       : A2p + (long)z * a2Slice + (long)(m0 + r) * 512 + (kg - 512);
      }
      gload16(a, &lA[c * 8]);
    }
#pragma unroll
    for (int i = 0; i < 4; i++) {
      const int c = i * 256 + tid;
      const int r = c >> 3;
      const int col = ((c & 7) ^ (r & 7)) << 3;
      gload16(bbase + (long)r * KTOT + (k0 + col), &lB[c * 8]);
    }
    __syncthreads();

#pragma unroll
    for (int ks = 0; ks < 2; ks++) {
      bf16x8 af[4], bfg[4];
      const int kc = ks * 32 + fk;
#pragma unroll
      for (int f = 0; f < 4; f++)
        af[f]  = *(const bf16x8*)&lA[(wm + f * 16 + fr) * 64 + (kc ^ xorkey)];
#pragma unroll
      for (int f = 0; f < 4; f++)
        bfg[f] = *(const bf16x8*)&lB[(wn + f * 16 + fr) * 64 + (kc ^ xorkey)];
#pragma unroll
      for (int fm = 0; fm < 4; fm++)
#pragma unroll
        for (int fn = 0; fn < 4; fn++)
          acc[fm][fn] = __builtin_amdgcn_mfma_f32_16x16x32_bf16(af[fm], bfg[fn], acc[fm][fn], 0, 0, 0);
    }
  }

  if constexpr (EPI == EPI_DOT) {
    const float* bsl = bias + (long)z * 512;
    const float* wsl = dotW + (long)z * 512;
#pragma unroll
    for (int fm = 0; fm < 4; fm++) {
#pragma unroll
      for (int j = 0; j < 4; j++) {
        float p = 0.f;
#pragma unroll
        for (int fn = 0; fn < 4; fn++) {
          int col = n0 + wn + fn * 16 + fr;
          float v = acc[fm][fn][j] + bsl[col];
          v = lrelu(v);
          p += v * wsl[col];
        }
        p += __shfl_xor(p, 1); p += __shfl_xor(p, 2); p += __shfl_xor(p, 4); p += __shfl_xor(p, 8);
        if (fr == 0) {
          long row = (long)z * 8192 + (m0 + wm + fm * 16 + rbase + j);
          partial[row * 8 + blockIdx.y * 2 + (wv & 1)] = p;
        }
      }
    }
  } else {
#pragma unroll
    for (int fm = 0; fm < 4; fm++) {
#pragma unroll
      for (int fn = 0; fn < 4; fn++) {
        int col = n0 + wn + fn * 16 + fr;
        float badd = 0.f; bool act = false;
        if (col >= 256) { badd = bias[col - 256]; act = true; }
        us16* op = outB + (long)z * outSlice + (long)(m0 + wm + fm * 16 + rbase) * outRow + col;
#pragma unroll
        for (int j = 0; j < 4; j++) {
          float v = acc[fm][fn][j] + badd;
          if (act) v = lrelu(v);
          op[(long)j * outRow] = f2bf(v);
        }
      }
    }
  }
}

// ---------------------------------------------------------------------------
// Tier A: fused 4-head KSV GEMM. grid (64, 12, 8): e = by/3, n0 = (by%3)*128.
// Output KSV4[b][e][agent][384]: idx = b*12288 + e*3072 + agent*384 + col.
// ---------------------------------------------------------------------------
__global__ __launch_bounds__(256, 4)
void ksv4_k(const us16* __restrict__ enc, const us16* __restrict__ wkvst,
            const float* __restrict__ bv, us16* __restrict__ ksv4)
{
  __shared__ us16 lA[128 * 64];
  __shared__ us16 lB[128 * 64];
  constexpr int KTOT = 512;
  const int tid = threadIdx.x;
  const int z = blockIdx.z;                    // agent
  const int e = blockIdx.y / 3;
  const int n0 = (blockIdx.y % 3) * 128;
  const int m0 = blockIdx.x * 128;
  const int wv = tid >> 6, lane = tid & 63;
  const int wm = (wv >> 1) * 64, wn = (wv & 1) * 64;
  const int fr = lane & 15, fk = (lane >> 4) * 8;
  const int rbase = (lane >> 4) * 4;
  const int xorkey = (fr & 7) << 3;

  f32x4 acc[4][4];
#pragma unroll
  for (int i = 0; i < 4; i++)
#pragma unroll
    for (int j = 0; j < 4; j++) acc[i][j] = f32x4{0.f, 0.f, 0.f, 0.f};

  const us16* abase = enc + (long)z * 8192 * 512 + (long)m0 * KTOT;
  const us16* bbase = wkvst + ((long)e * 384 + n0) * KTOT;

  for (int k0 = 0; k0 < KTOT; k0 += 64) {
    __syncthreads();
#pragma unroll
    for (int i = 0; i < 4; i++) {
      const int c = i * 256 + tid;
      const int r = c >> 3;
      const int col = ((c & 7) ^ (r & 7)) << 3;
      gload16(abase + (long)r * KTOT + (k0 + col), &lA[c * 8]);
    }
#pragma unroll
    for (int i = 0; i < 4; i++) {
      const int c = i * 256 + tid;
      const int r = c >> 3;
      const int col = ((c & 7) ^ (r & 7)) << 3;
      gload16(bbase + (long)r * KTOT + (k0 + col), &lB[c * 8]);
    }
    __syncthreads();

#pragma unroll
    for (int ks = 0; ks < 2; ks++) {
      bf16x8 af[4], bfg[4];
      const int kc = ks * 32 + fk;
#pragma unroll
      for (int f = 0; f < 4; f++)
        af[f]  = *(const bf16x8*)&lA[(wm + f * 16 + fr) * 64 + (kc ^ xorkey)];
#pragma unroll
      for (int f = 0; f < 4; f++)
        bfg[f] = *(const bf16x8*)&lB[(wn + f * 16 + fr) * 64 + (kc ^ xorkey)];
#pragma unroll
      for (int fm = 0; fm < 4; fm++)
#pragma unroll
        for (int fn = 0; fn < 4; fn++)
          acc[fm][fn] = __builtin_amdgcn_mfma_f32_16x16x32_bf16(af[fm], bfg[fn], acc[fm][fn], 0, 0, 0);
    }
  }

#pragma unroll
  for (int fm = 0; fm < 4; fm++) {
#pragma unroll
    for (int fn = 0; fn < 4; fn++) {
      int col = n0 + wn + fn * 16 + fr;          // 0..383 within head
      float badd = 0.f; bool act = false;
      if (col >= 256) { badd = bv[e * 128 + (col - 256)]; act = true; }
      us16* op = ksv4 + (long)(m0 + wm + fm * 16 + rbase) * 12288 + e * 3072 + z * 384 + col;
#pragma unroll
      for (int j = 0; j < 4; j++) {
        float v = acc[fm][fn][j] + badd;
        if (act) v = lrelu(v);
        op[(long)j * 12288] = f2bf(v);
      }
    }
  }
}

// ---------------------------------------------------------------------------
// Tier A: fused 2-MLP DOT GEMM. grid (64, 4, 16): zz<8 -> critic, else value.
// ---------------------------------------------------------------------------
__global__ __launch_bounds__(256, 4)
void dot2_k(const us16* __restrict__ encC, const us16* __restrict__ encV,
            const us16* __restrict__ other,
            const us16* __restrict__ wc1t, const us16* __restrict__ wv1t,
            const float* __restrict__ bc1, const float* __restrict__ bv1,
            const float* __restrict__ wc2, const float* __restrict__ wv2,
            float* __restrict__ partial)
{
  __shared__ us16 lA[128 * 64];
  __shared__ us16 lB[128 * 64];
  constexpr int KTOT = 1024;
  const int tid = threadIdx.x;
  const int zz = blockIdx.z;
  const int half = zz >> 3, z = zz & 7;
  const us16* Ap  = half ? encV : encC;
  const us16* Btp = half ? wv1t : wc1t;
  const float* bias = half ? bv1 : bc1;
  const float* dotW = half ? wv2 : wc2;
  const int m0 = blockIdx.x * 128;
  const int n0 = blockIdx.y * 128;
  const int wv = tid >> 6, lane = tid & 63;
  const int wm = (wv >> 1) * 64, wn = (wv & 1) * 64;
  const int fr = lane & 15, fk = (lane >> 4) * 8;
  const int rbase = (lane >> 4) * 4;
  const int xorkey = (fr & 7) << 3;

  f32x4 acc[4][4];
#pragma unroll
  for (int i = 0; i < 4; i++)
#pragma unroll
    for (int j = 0; j < 4; j++) acc[i][j] = f32x4{0.f, 0.f, 0.f, 0.f};

  const us16* bbase = Btp + (long)z * 512 * 1024 + (long)n0 * KTOT;
  const long aSlice = (long)8192 * 512;

  for (int k0 = 0; k0 < KTOT; k0 += 64) {
    __syncthreads();
#pragma unroll
    for (int i = 0; i < 4; i++) {
      const int c = i * 256 + tid;
      const int r = c >> 3;
      const int col = ((c & 7) ^ (r & 7)) << 3;
      const int kg = k0 + col;
      const us16* a = (kg < 512) ? Ap    + (long)z * aSlice + (long)(m0 + r) * 512 + kg
                                 : other + (long)z * aSlice + (long)(m0 + r) * 512 + (kg - 512);
      gload16(a, &lA[c * 8]);
    }
#pragma unroll
    for (int i = 0; i < 4; i++) {
      const int c = i * 256 + tid;
      const int r = c >> 3;
      const int col = ((c & 7) ^ (r & 7)) << 3;
      gload16(bbase + (long)r * KTOT + (k0 + col), &lB[c * 8]);
    }
    __syncthreads();

#pragma unroll
    for (int ks = 0; ks < 2; ks++) {
      bf16x8 af[4], bfg[4];
      const int kc = ks * 32 + fk;
#pragma unroll
      for (int f = 0; f < 4; f++)
        af[f]  = *(const bf16x8*)&lA[(wm + f * 16 + fr) * 64 + (kc ^ xorkey)];
#pragma unroll
      for (int f = 0; f < 4; f++)
        bfg[f] = *(const bf16x8*)&lB[(wn + f * 16 + fr) * 64 + (kc ^ xorkey)];
#pragma unroll
      for (int fm = 0; fm < 4; fm++)
#pragma unroll
        for (int fn = 0; fn < 4; fn++)
          acc[fm][fn] = __builtin_amdgcn_mfma_f32_16x16x32_bf16(af[fm], bfg[fn], acc[fm][fn], 0, 0, 0);
    }
  }

  const float* bsl = bias + (long)z * 512;
  const float* wsl = dotW + (long)z * 512;
#pragma unroll
  for (int fm = 0; fm < 4; fm++) {
#pragma unroll
    for (int j = 0; j < 4; j++) {
      float p = 0.f;
#pragma unroll
      for (int fn = 0; fn < 4; fn++) {
        int col = n0 + wn + fn * 16 + fr;
        float v = acc[fm][fn][j] + bsl[col];
        v = lrelu(v);
        p += v * wsl[col];
      }
      p += __shfl_xor(p, 1); p += __shfl_xor(p, 2); p += __shfl_xor(p, 4); p += __shfl_xor(p, 8);
      if (fr == 0) {
        long row = (long)half * 65536 + (long)z * 8192 + (m0 + wm + fm * 16 + rbase + j);
        partial[row * 8 + blockIdx.y * 2 + (wv & 1)] = p;
      }
    }
  }
}

// ---------------------------------------------------------------------------
// Attention. Tier B form (per-head buffer) and Tier A fused form (KSV4).
// ---------------------------------------------------------------------------
DEVI void attn_core(const us16* __restrict__ src, us16* __restrict__ other,
                    int e, long b, int wv, int lane, us16* tbuf)
{
#pragma unroll
  for (int i = 0; i < 6; i++) {
    int c = i * 64 + lane;
    int r = c / 48, cc = c - r * 48;
    *(int4*)&tbuf[r * 392 + cc * 8] = *(const int4*)&src[c * 8];
  }
  __syncthreads();
  const int i = lane >> 3, j = lane & 7;
  const us16* selp = &tbuf[i * 392 + 128];
  const us16* keyp = &tbuf[j * 392];
  float acc = 0.f;
#pragma unroll
  for (int d = 0; d < 128; d += 8) {
    u16x8 s8 = *(const u16x8*)&selp[d];
    u16x8 k8 = *(const u16x8*)&keyp[d];
#pragma unroll
    for (int q = 0; q < 8; q++) acc += bf2f(s8[q]) * bf2f(k8[q]);
  }
  acc *= 0.088388347648318447f;
  float mx = acc;
  mx = fmaxf(mx, __shfl_xor(mx, 1)); mx = fmaxf(mx, __shfl_xor(mx, 2)); mx = fmaxf(mx, __shfl_xor(mx, 4));
  float ex = __expf(acc - mx);
  float sm = ex;
  sm += __shfl_xor(sm, 1); sm += __shfl_xor(sm, 2); sm += __shfl_xor(sm, 4);
  float wsm = ex / sm;
  float wj[8];
  const int ibase = lane & 56;
#pragma unroll
  for (int jj = 0; jj < 8; jj++) wj[jj] = __shfl(wsm, ibase + jj);
  const int dbase = (lane & 7) * 16;
  float o[16];
#pragma unroll
  for (int q = 0; q < 16; q++) o[q] = 0.f;
#pragma unroll
  for (int jj = 0; jj < 8; jj++) {
    u16x8 v0 = *(const u16x8*)&tbuf[jj * 392 + 256 + dbase];
    u16x8 v1 = *(const u16x8*)&tbuf[jj * 392 + 256 + dbase + 8];
    float wgt = wj[jj];
#pragma unroll
    for (int q = 0; q < 8; q++) { o[q] += wgt * bf2f(v0[q]); o[8 + q] += wgt * bf2f(v1[q]); }
  }
  u16x8 r0, r1;
#pragma unroll
  for (int q = 0; q < 8; q++) { r0[q] = f2bf(o[q]); r1[q] = f2bf(o[8 + q]); }
  us16* dst = other + ((long)i * 8192 + b) * 512 + e * 128 + dbase;
  *(u16x8*)&dst[0] = r0;
  *(u16x8*)&dst[8] = r1;
}

__global__ __launch_bounds__(256, 4)
void attn_k(const us16* __restrict__ ksv, us16* __restrict__ other, int e)
{
  __shared__ us16 t[4][8 * 392];
  const int wv = threadIdx.x >> 6, lane = threadIdx.x & 63;
  const long b = (long)blockIdx.x * 4 + wv;
  attn_core(ksv + b * 3072, other, e, b, wv, lane, &t[wv][0]);
}

__global__ __launch_bounds__(256, 4)
void attn4_k(const us16* __restrict__ ksv4, us16* __restrict__ other)
{
  __shared__ us16 t[4][8 * 392];
  const int wv = threadIdx.x >> 6, lane = threadIdx.x & 63;
  const long b = (long)blockIdx.x * 4 + wv;
  const int e = blockIdx.y;
  attn_core(ksv4 + b * 12288 + e * 3072, other, e, b, wv, lane, &t[wv][0]);
}

// merged final reduce: r < 65536 -> q (bc2), else v (bv2). grid 512 x 256.
__global__ void reduce2_k(const float* __restrict__ part, const float* __restrict__ b2c,
                          const float* __restrict__ b2v, float* __restrict__ out)
{
  int r = blockIdx.x * 256 + threadIdx.x;   // 0..131071
  const float4* p = (const float4*)(part + (long)r * 8);
  float4 a = p[0], b = p[1];
  float s = ((a.x + a.y) + (a.z + a.w)) + ((b.x + b.y) + (b.z + b.w));
  int agent = (r >> 13) & 7;
  out[r] = s + ((r < 65536) ? b2c[agent] : b2v[agent]);
}

// ---------------------------------------------------------------------------
extern "C" void kernel_launch(void* const* d_in, const int* in_sizes, int n_in,
                              void* d_out, int out_size, void* d_ws, size_t ws_size,
                              hipStream_t stream)
{
  const float* states = (const float*)d_in[0];
  const float* actions= (const float*)d_in[1];
  const float* Ws  = (const float*)d_in[2];
  const float* bs  = (const float*)d_in[3];
  const float* Wsa = (const float*)d_in[4];
  const float* bsa = (const float*)d_in[5];
  const float* Wk  = (const float*)d_in[6];
  const float* Wsel= (const float*)d_in[7];
  const float* Wv  = (const float*)d_in[8];
  const float* bv  = (const float*)d_in[9];
  const float* Wc1 = (const float*)d_in[10];
  const float* bc1 = (const float*)d_in[11];
  const float* Wc2 = (const float*)d_in[12];
  const float* bc2 = (const float*)d_in[13];
  const float* Wv1 = (const float*)d_in[14];
  const float* bv1 = (const float*)d_in[15];
  const float* Wv2 = (const float*)d_in[16];
  const float* bv2 = (const float*)d_in[17];

  char* ws = (char*)d_ws;
  constexpr size_t OFF_WST   = 0;
  constexpr size_t OFF_WSAT  = OFF_WST   + (size_t)8 * 512 * 64 * 2;
  constexpr size_t OFF_WKVST = OFF_WSAT  + (size_t)8 * 512 * 96 * 2;
  constexpr size_t OFF_WC1T  = OFF_WKVST + (size_t)4 * 384 * 512 * 2;
  constexpr size_t OFF_WV1T  = OFF_WC1T  + (size_t)8 * 512 * 1024 * 2;
  constexpr size_t OFF_ENC   = OFF_WV1T  + (size_t)8 * 512 * 1024 * 2;
  constexpr size_t OFF_OTHER = OFF_ENC   + (size_t)8 * 8192 * 512 * 2;
  constexpr size_t OFF_KSV   = OFF_OTHER + (size_t)8 * 8192 * 512 * 2;
  // Tier B: KSV (one head, 50.3 MB) + PART
  constexpr size_t OFF_PARTB = OFF_KSV   + (size_t)8192 * 8 * 384 * 2;
  constexpr size_t NEED_B    = OFF_PARTB + (size_t)131072 * 8 * 4;
  // Tier A: KSV4 (all heads, 201.3 MB) + PART + ENC2
  constexpr size_t OFF_PARTA = OFF_KSV   + (size_t)65536 * 1536 * 2;
  constexpr size_t OFF_ENC2  = OFF_PARTA + (size_t)131072 * 8 * 4;
  constexpr size_t NEED_A    = OFF_ENC2  + (size_t)8 * 8192 * 512 * 2;
  if (ws_size < NEED_B) return;
  const bool bigws = (ws_size >= NEED_A);

  us16* WST   = (us16*)(ws + OFF_WST);
  us16* WSAT  = (us16*)(ws + OFF_WSAT);
  us16* WKVST = (us16*)(ws + OFF_WKVST);
  us16* WC1T  = (us16*)(ws + OFF_WC1T);
  us16* WV1T  = (us16*)(ws + OFF_WV1T);
  us16* ENC   = (us16*)(ws + OFF_ENC);
  us16* OTHER = (us16*)(ws + OFF_OTHER);
  us16* KSV   = (us16*)(ws + OFF_KSV);      // tier B: one head; tier A: KSV4
  float* PARTB= (float*)(ws + OFF_PARTB);
  float* PARTA= (float*)(ws + OFF_PARTA);
  us16* ENC2  = (us16*)(ws + OFF_ENC2);

  dim3 tb(32, 8);
  tconvSA_k<<<dim3(3, 16, 16), tb, 0, stream>>>(Ws, Wsa, WST, WSAT);
  tconv3_k <<<dim3(16, 4, 12), tb, 0, stream>>>(Wk, Wsel, Wv, WKVST);
  tconvC_k <<<dim3(32, 16, 16),tb, 0, stream>>>(Wc1, Wv1, WC1T, WV1T);

  // sa_enc = lrelu([states|actions] @ Wsa + bsa)  -> ENC (bf16)
  enc_gemm_k<ASRC_F32_CAT, 96><<<dim3(64, 4, 8), 256, 0, stream>>>(
      states, (long)8192 * 64, actions, (long)8192 * 16, WSAT, (long)512 * 96, bsa, 512,
      ENC, (long)8192 * 512, 512);

  if (bigws) {
    // s_enc -> ENC2 (independent; launch early for overlap headroom)
    enc_gemm_k<ASRC_F32, 64><<<dim3(64, 4, 8), 256, 0, stream>>>(
        states, (long)8192 * 64, nullptr, 0, WST, (long)512 * 64, bs, 512,
        ENC2, (long)8192 * 512, 512);
    // all 4 heads' KSV in one dispatch
    ksv4_k<<<dim3(64, 12, 8), 256, 0, stream>>>(ENC, WKVST, bv, KSV);
    // all 4 heads' attention in one dispatch
    attn4_k<<<dim3(2048, 4), 256, 0, stream>>>(KSV, OTHER);
    // both MLP heads in one dispatch
    dot2_k<<<dim3(64, 4, 16), 256, 0, stream>>>(
        ENC, ENC2, OTHER, WC1T, WV1T, bc1, bv1, Wc2, Wv2, PARTA);
    reduce2_k<<<dim3(512), 256, 0, stream>>>(PARTA, bc2, bv2, (float*)d_out);
  } else {
    for (int e = 0; e < 4; e++) {
      gemm64_k<false, EPI_KSV, 512><<<dim3(64, 3, 8), 256, 0, stream>>>(
          ENC, (long)8192 * 512, nullptr, 0, WKVST + (size_t)e * 384 * 512, 0, bv + e * 128,
          KSV, 384, 3072, nullptr, nullptr);
      attn_k<<<dim3(2048), 256, 0, stream>>>(KSV, OTHER, e);
    }
    gemm64_k<true, EPI_DOT, 1024><<<dim3(64, 4, 8), 256, 0, stream>>>(
        ENC, (long)8192 * 512, OTHER, (long)8192 * 512, WC1T, (long)512 * 1024, bc1,
        nullptr, 0, 0, Wc2, PARTB);
    enc_gemm_k<ASRC_F32, 64><<<dim3(64, 4, 8), 256, 0, stream>>>(
        states, (long)8192 * 64, nullptr, 0, WST, (long)512 * 64, bs, 512,
        ENC, (long)8192 * 512, 512);
    gemm64_k<true, EPI_DOT, 1024><<<dim3(64, 4, 8), 256, 0, stream>>>(
        ENC, (long)8192 * 512, OTHER, (long)8192 * 512, WV1T, (long)512 * 1024, bv1,
        nullptr, 0, 0, Wv2, PARTB + (size_t)65536 * 8);
    reduce2_k<<<dim3(512), 256, 0, stream>>>(PARTB, bc2, bv2, (float*)d_out);
  }
}

// Round 10
// 393.332 us; speedup vs baseline: 1.1668x; 1.0619x over previous
//
#include <hip/hip_runtime.h>

// ---------------------------------------------------------------------------
// AttentionCritic on MI355X — round 10: fusion tier that fits.
// Tier A2 (~255 MB): heads processed in PAIRS (ksv2 = 3072 blocks = 3 exact
// occupancy rounds, no drain tail), PART/ENC2 aliased into the dead KSV2
// region, both MLP DOTs fused. Tier B (~208 MB): round-9 proven structure.
// ---------------------------------------------------------------------------

#define DEVI __device__ __forceinline__

typedef unsigned short us16;
typedef __bf16 bf16x8 __attribute__((ext_vector_type(8)));
typedef float f32x4 __attribute__((ext_vector_type(4)));
typedef unsigned short u16x8 __attribute__((ext_vector_type(8)));

DEVI us16 f2bf(float f) {
  unsigned u = __builtin_bit_cast(unsigned, f);
  u += 0x7FFFu + ((u >> 16) & 1u);          // round-to-nearest-even
  return (us16)(u >> 16);
}
DEVI float bf2f(us16 h) {
  unsigned u = ((unsigned)h) << 16;
  return __builtin_bit_cast(float, u);
}
DEVI float lrelu(float v) { return v > 0.f ? v : 0.01f * v; }
DEVI int pk2(float a, float b) { return (int)f2bf(a) | ((int)f2bf(b) << 16); }

// async global->LDS, 16B per lane. LDS dest must be linear: base + lane*16.
DEVI void gload16(const us16* g, us16* l) {
  __builtin_amdgcn_global_load_lds(
      (const __attribute__((address_space(1))) void*)g,
      (__attribute__((address_space(3))) void*)l, 16, 0, 0);
}

// ---------------------------------------------------------------------------
// Transposes (fp32 -> bf16, [K][O] -> [O][Kpad])
// ---------------------------------------------------------------------------
__global__ void tconvSA_k(const float* __restrict__ wsrc, const float* __restrict__ wsasrc,
                          us16* __restrict__ wst, us16* __restrict__ wsat)
{
  __shared__ float t[32][33];
  const int zz = blockIdx.z;               // 0..15
  const int m = zz >> 3, s = zz & 7;
  const int K = m ? 80 : 64, Kpad = m ? 96 : 64;
  const float* src = m ? (wsasrc + (long)s * 80 * 512) : (wsrc + (long)s * 64 * 512);
  us16* dst = m ? (wsat + (long)s * 512 * 96) : (wst + (long)s * 512 * 64);
  const int k0 = blockIdx.x * 32, o0 = blockIdx.y * 32;
  const int lx = threadIdx.x, ly = threadIdx.y;
#pragma unroll
  for (int i = 0; i < 4; i++) {
    int k = k0 + ly + i * 8, o = o0 + lx;
    float v = 0.f;
    if (k < K) v = src[(long)k * 512 + o];
    t[ly + i * 8][lx] = v;
  }
  __syncthreads();
#pragma unroll
  for (int i = 0; i < 4; i++) {
    int o = o0 + ly + i * 8, k = k0 + lx;
    if (k < Kpad)
      dst[(long)o * Kpad + k] = f2bf(t[lx][ly + i * 8]);
  }
}

__global__ void tconv3_k(const float* __restrict__ wk, const float* __restrict__ wsel,
                         const float* __restrict__ wv, us16* __restrict__ dst)
{
  __shared__ float t[32][33];
  const int zz = blockIdx.z;               // 0..11
  const int e = zz & 3, m = zz >> 2;       // m: 0=key 1=sel 2=val
  const float* src = ((m == 0) ? wk : (m == 1) ? wsel : wv) + (long)e * 512 * 128;
  us16* d = dst + (long)e * 384 * 512 + (long)(m * 128) * 512;
  const int k0 = blockIdx.x * 32, o0 = blockIdx.y * 32;
  const int lx = threadIdx.x, ly = threadIdx.y;
#pragma unroll
  for (int i = 0; i < 4; i++)
    t[ly + i * 8][lx] = src[(long)(k0 + ly + i * 8) * 128 + (o0 + lx)];
  __syncthreads();
#pragma unroll
  for (int i = 0; i < 4; i++)
    d[(long)(o0 + ly + i * 8) * 512 + (k0 + lx)] = f2bf(t[lx][ly + i * 8]);
}

__global__ void tconvC_k(const float* __restrict__ c1, const float* __restrict__ v1,
                         us16* __restrict__ dc, us16* __restrict__ dv)
{
  __shared__ float t[32][33];
  const int zz = blockIdx.z;               // 0..15
  const int n = zz & 7, m = zz >> 3;
  const float* src = ((m == 0) ? c1 : v1) + (long)n * 1024 * 512;
  us16* dst = ((m == 0) ? dc : dv) + (long)n * 512 * 1024;
  const int k0 = blockIdx.x * 32, o0 = blockIdx.y * 32;
  const int lx = threadIdx.x, ly = threadIdx.y;
#pragma unroll
  for (int i = 0; i < 4; i++)
    t[ly + i * 8][lx] = src[(long)(k0 + ly + i * 8) * 512 + (o0 + lx)];
  __syncthreads();
#pragma unroll
  for (int i = 0; i < 4; i++)
    dst[(long)(o0 + ly + i * 8) * 1024 + (k0 + lx)] = f2bf(t[lx][ly + i * 8]);
}

// ---------------------------------------------------------------------------
// fp32-input encoder GEMM (proven, BK=32, linear LDS).
// ---------------------------------------------------------------------------
enum { ASRC_F32 = 2, ASRC_F32_CAT = 3 };

template <int ASRC, int KTOT>
__global__ __launch_bounds__(256, 4)
void enc_gemm_k(const float* __restrict__ Ap, long aSlice,
                const float* __restrict__ A2p, long a2Slice,
                const us16* __restrict__ Btp, long bSlice,
                const float* __restrict__ bias, long biasSlice,
                us16* __restrict__ outB, long outSlice, long outRow)
{
  __shared__ us16 lA[128 * 32];
  __shared__ us16 lB[128 * 32];
  const int tid = threadIdx.x;
  const int z = blockIdx.z;
  const int m0 = blockIdx.x * 128;
  const int n0 = blockIdx.y * 128;
  const int wv = tid >> 6, lane = tid & 63;
  const int wm = (wv >> 1) * 64, wn = (wv & 1) * 64;
  const int fr = lane & 15, fk = (lane >> 4) * 8;
  const int rbase = (lane >> 4) * 4;
  const int grow = tid >> 2, gcol = (tid & 3) * 8;

  f32x4 acc[4][4];
#pragma unroll
  for (int i = 0; i < 4; i++)
#pragma unroll
    for (int j = 0; j < 4; j++) acc[i][j] = f32x4{0.f, 0.f, 0.f, 0.f};

  const us16* bbase = Btp + (long)z * bSlice + (long)n0 * KTOT;

  for (int k0 = 0; k0 < KTOT; k0 += 32) {
    int4 ra0, ra1;
    {
      const int srow = tid >> 1, scol0 = (tid & 1) * 16;
      const int kg = k0 + scol0;
      const float* a = nullptr;
      if constexpr (ASRC == ASRC_F32) {
        a = Ap + (long)z * aSlice + (long)(m0 + srow) * 64 + kg;
      } else {  // states(0..63) | actions(64..79) | zero pad(80..95)
        if (kg < 64)      a = Ap + (long)z * aSlice + (long)(m0 + srow) * 64 + kg;
        else if (kg < 80) a = A2p + (long)z * a2Slice + (long)(m0 + srow) * 16 + (kg - 64);
      }
      float4 f0, f1, f2, f3;
      if (a) { const float4* ap = (const float4*)a; f0 = ap[0]; f1 = ap[1]; f2 = ap[2]; f3 = ap[3]; }
      else   { f0 = make_float4(0.f, 0.f, 0.f, 0.f); f1 = f0; f2 = f0; f3 = f0; }
      ra0.x = pk2(f0.x, f0.y); ra0.y = pk2(f0.z, f0.w); ra0.z = pk2(f1.x, f1.y); ra0.w = pk2(f1.z, f1.w);
      ra1.x = pk2(f2.x, f2.y); ra1.y = pk2(f2.z, f2.w); ra1.z = pk2(f3.x, f3.y); ra1.w = pk2(f3.z, f3.w);
    }

    __syncthreads();
    {
      const us16* bb = bbase + k0 + gcol;
      gload16(bb + (long)grow * KTOT, &lB[tid * 8]);
      gload16(bb + (long)(64 + grow) * KTOT, &lB[2048 + tid * 8]);
    }
    {
      const int srow = tid >> 1, scol0 = (tid & 1) * 16;
      *(int4*)&lA[srow * 32 + scol0]     = ra0;
      *(int4*)&lA[srow * 32 + scol0 + 8] = ra1;
    }
    __syncthreads();

    bf16x8 af[4], bfg[4];
#pragma unroll
    for (int f = 0; f < 4; f++) af[f]  = *(const bf16x8*)&lA[(wm + f * 16 + fr) * 32 + fk];
#pragma unroll
    for (int f = 0; f < 4; f++) bfg[f] = *(const bf16x8*)&lB[(wn + f * 16 + fr) * 32 + fk];
#pragma unroll
    for (int fm = 0; fm < 4; fm++)
#pragma unroll
      for (int fn = 0; fn < 4; fn++)
        acc[fm][fn] = __builtin_amdgcn_mfma_f32_16x16x32_bf16(af[fm], bfg[fn], acc[fm][fn], 0, 0, 0);
  }

#pragma unroll
  for (int fm = 0; fm < 4; fm++) {
#pragma unroll
    for (int fn = 0; fn < 4; fn++) {
      int col = n0 + wn + fn * 16 + fr;
      float badd = bias[(long)z * biasSlice + col];
      us16* op = outB + (long)z * outSlice + (long)(m0 + wm + fm * 16 + rbase) * outRow + col;
#pragma unroll
      for (int j = 0; j < 4; j++) {
        float v = lrelu(acc[fm][fn][j] + badd);
        op[(long)j * outRow] = f2bf(v);
      }
    }
  }
}

// ---------------------------------------------------------------------------
// Proven 128^2 bf16 GEMM (BK=64, XOR-swizzle, 2-barrier) — Tier B forms.
// ---------------------------------------------------------------------------
enum { EPI_KSV = 1, EPI_DOT = 2 };

template <bool CAT, int EPI, int KTOT>
__global__ __launch_bounds__(256, 4)
void gemm64_k(const us16* __restrict__ Ap, long aSlice,
              const us16* __restrict__ A2p, long a2Slice,
              const us16* __restrict__ Btp, long bSlice,
              const float* __restrict__ bias,
              us16* __restrict__ outB, long outSlice, long outRow,
              const float* __restrict__ dotW, float* __restrict__ partial)
{
  __shared__ us16 lA[128 * 64];
  __shared__ us16 lB[128 * 64];
  const int tid = threadIdx.x;
  const int z = blockIdx.z;
  const int m0 = blockIdx.x * 128;
  const int n0 = blockIdx.y * 128;
  const int wv = tid >> 6, lane = tid & 63;
  const int wm = (wv >> 1) * 64, wn = (wv & 1) * 64;
  const int fr = lane & 15, fk = (lane >> 4) * 8;
  const int rbase = (lane >> 4) * 4;
  const int xorkey = (fr & 7) << 3;

  f32x4 acc[4][4];
#pragma unroll
  for (int i = 0; i < 4; i++)
#pragma unroll
    for (int j = 0; j < 4; j++) acc[i][j] = f32x4{0.f, 0.f, 0.f, 0.f};

  const us16* bbase = Btp + (long)z * bSlice + (long)n0 * KTOT;

  for (int k0 = 0; k0 < KTOT; k0 += 64) {
    __syncthreads();
#pragma unroll
    for (int i = 0; i < 4; i++) {
      const int c = i * 256 + tid;
      const int r = c >> 3;
      const int col = ((c & 7) ^ (r & 7)) << 3;
      const us16* a;
      if constexpr (!CAT) {
        a = Ap + (long)z * aSlice + (long)(m0 + r) * KTOT + (k0 + col);
      } else {
        const int kg = k0 + col;
        a = (kg < 512) ? Ap  + (long)z * aSlice  + (long)(m0 + r) * 512 + kg
                       : A2p + (long)z * a2Slice + (long)(m0 + r) * 512 + (kg - 512);
      }
      gload16(a, &lA[c * 8]);
    }
#pragma unroll
    for (int i = 0; i < 4; i++) {
      const int c = i * 256 + tid;
      const int r = c >> 3;
      const int col = ((c & 7) ^ (r & 7)) << 3;
      gload16(bbase + (long)r * KTOT + (k0 + col), &lB[c * 8]);
    }
    __syncthreads();

#pragma unroll
    for (int ks = 0; ks < 2; ks++) {
      bf16x8 af[4], bfg[4];
      const int kc = ks * 32 + fk;
#pragma unroll
      for (int f = 0; f < 4; f++)
        af[f]  = *(const bf16x8*)&lA[(wm + f * 16 + fr) * 64 + (kc ^ xorkey)];
#pragma unroll
      for (int f = 0; f < 4; f++)
        bfg[f] = *(const bf16x8*)&lB[(wn + f * 16 + fr) * 64 + (kc ^ xorkey)];
#pragma unroll
      for (int fm = 0; fm < 4; fm++)
#pragma unroll
        for (int fn = 0; fn < 4; fn++)
          acc[fm][fn] = __builtin_amdgcn_mfma_f32_16x16x32_bf16(af[fm], bfg[fn], acc[fm][fn], 0, 0, 0);
    }
  }

  if constexpr (EPI == EPI_DOT) {
    const float* bsl = bias + (long)z * 512;
    const float* wsl = dotW + (long)z * 512;
#pragma unroll
    for (int fm = 0; fm < 4; fm++) {
#pragma unroll
      for (int j = 0; j < 4; j++) {
        float p = 0.f;
#pragma unroll
        for (int fn = 0; fn < 4; fn++) {
          int col = n0 + wn + fn * 16 + fr;
          float v = acc[fm][fn][j] + bsl[col];
          v = lrelu(v);
          p += v * wsl[col];
        }
        p += __shfl_xor(p, 1); p += __shfl_xor(p, 2); p += __shfl_xor(p, 4); p += __shfl_xor(p, 8);
        if (fr == 0) {
          long row = (long)z * 8192 + (m0 + wm + fm * 16 + rbase + j);
          partial[row * 8 + blockIdx.y * 2 + (wv & 1)] = p;
        }
      }
    }
  } else {
#pragma unroll
    for (int fm = 0; fm < 4; fm++) {
#pragma unroll
      for (int fn = 0; fn < 4; fn++) {
        int col = n0 + wn + fn * 16 + fr;
        float badd = 0.f; bool act = false;
        if (col >= 256) { badd = bias[col - 256]; act = true; }
        us16* op = outB + (long)z * outSlice + (long)(m0 + wm + fm * 16 + rbase) * outRow + col;
#pragma unroll
        for (int j = 0; j < 4; j++) {
          float v = acc[fm][fn][j] + badd;
          if (act) v = lrelu(v);
          op[(long)j * outRow] = f2bf(v);
        }
      }
    }
  }
}

// ---------------------------------------------------------------------------
// Tier A2: 2-head fused KSV GEMM. grid (64, 6, 8): el = by/3, n0 = (by%3)*128.
// Output KSV2[b][el*3072 + agent*384 + col], row stride 6144.
// 3072 blocks = exactly 3 occupancy rounds at 4 blocks/CU.
// ---------------------------------------------------------------------------
__global__ __launch_bounds__(256, 4)
void ksv2_k(const us16* __restrict__ enc, const us16* __restrict__ wkvst2,
            const float* __restrict__ bv2h, us16* __restrict__ ksv2)
{
  __shared__ us16 lA[128 * 64];
  __shared__ us16 lB[128 * 64];
  constexpr int KTOT = 512;
  const int tid = threadIdx.x;
  const int z = blockIdx.z;                    // agent
  const int el = blockIdx.y / 3;               // head within pair
  const int n0 = (blockIdx.y % 3) * 128;
  const int m0 = blockIdx.x * 128;
  const int wv = tid >> 6, lane = tid & 63;
  const int wm = (wv >> 1) * 64, wn = (wv & 1) * 64;
  const int fr = lane & 15, fk = (lane >> 4) * 8;
  const int rbase = (lane >> 4) * 4;
  const int xorkey = (fr & 7) << 3;

  f32x4 acc[4][4];
#pragma unroll
  for (int i = 0; i < 4; i++)
#pragma unroll
    for (int j = 0; j < 4; j++) acc[i][j] = f32x4{0.f, 0.f, 0.f, 0.f};

  const us16* abase = enc + (long)z * 8192 * 512 + (long)m0 * KTOT;
  const us16* bbase = wkvst2 + ((long)el * 384 + n0) * KTOT;

  for (int k0 = 0; k0 < KTOT; k0 += 64) {
    __syncthreads();
#pragma unroll
    for (int i = 0; i < 4; i++) {
      const int c = i * 256 + tid;
      const int r = c >> 3;
      const int col = ((c & 7) ^ (r & 7)) << 3;
      gload16(abase + (long)r * KTOT + (k0 + col), &lA[c * 8]);
    }
#pragma unroll
    for (int i = 0; i < 4; i++) {
      const int c = i * 256 + tid;
      const int r = c >> 3;
      const int col = ((c & 7) ^ (r & 7)) << 3;
      gload16(bbase + (long)r * KTOT + (k0 + col), &lB[c * 8]);
    }
    __syncthreads();

#pragma unroll
    for (int ks = 0; ks < 2; ks++) {
      bf16x8 af[4], bfg[4];
      const int kc = ks * 32 + fk;
#pragma unroll
      for (int f = 0; f < 4; f++)
        af[f]  = *(const bf16x8*)&lA[(wm + f * 16 + fr) * 64 + (kc ^ xorkey)];
#pragma unroll
      for (int f = 0; f < 4; f++)
        bfg[f] = *(const bf16x8*)&lB[(wn + f * 16 + fr) * 64 + (kc ^ xorkey)];
#pragma unroll
      for (int fm = 0; fm < 4; fm++)
#pragma unroll
        for (int fn = 0; fn < 4; fn++)
          acc[fm][fn] = __builtin_amdgcn_mfma_f32_16x16x32_bf16(af[fm], bfg[fn], acc[fm][fn], 0, 0, 0);
    }
  }

#pragma unroll
  for (int fm = 0; fm < 4; fm++) {
#pragma unroll
    for (int fn = 0; fn < 4; fn++) {
      int col = n0 + wn + fn * 16 + fr;          // 0..383 within head
      float badd = 0.f; bool act = false;
      if (col >= 256) { badd = bv2h[el * 128 + (col - 256)]; act = true; }
      us16* op = ksv2 + (long)(m0 + wm + fm * 16 + rbase) * 6144 + el * 3072 + z * 384 + col;
#pragma unroll
      for (int j = 0; j < 4; j++) {
        float v = acc[fm][fn][j] + badd;
        if (act) v = lrelu(v);
        op[(long)j * 6144] = f2bf(v);
      }
    }
  }
}

// ---------------------------------------------------------------------------
// Tier A2: fused 2-MLP DOT GEMM. grid (64, 4, 16): zz<8 -> critic, else value.
// ---------------------------------------------------------------------------
__global__ __launch_bounds__(256, 4)
void dot2_k(const us16* __restrict__ encC, const us16* __restrict__ encV,
            const us16* __restrict__ other,
            const us16* __restrict__ wc1t, const us16* __restrict__ wv1t,
            const float* __restrict__ bc1, const float* __restrict__ bv1,
            const float* __restrict__ wc2, const float* __restrict__ wv2,
            float* __restrict__ partial)
{
  __shared__ us16 lA[128 * 64];
  __shared__ us16 lB[128 * 64];
  constexpr int KTOT = 1024;
  const int tid = threadIdx.x;
  const int zz = blockIdx.z;
  const int half = zz >> 3, z = zz & 7;
  const us16* Ap  = half ? encV : encC;
  const us16* Btp = half ? wv1t : wc1t;
  const float* bias = half ? bv1 : bc1;
  const float* dotW = half ? wv2 : wc2;
  const int m0 = blockIdx.x * 128;
  const int n0 = blockIdx.y * 128;
  const int wv = tid >> 6, lane = tid & 63;
  const int wm = (wv >> 1) * 64, wn = (wv & 1) * 64;
  const int fr = lane & 15, fk = (lane >> 4) * 8;
  const int rbase = (lane >> 4) * 4;
  const int xorkey = (fr & 7) << 3;

  f32x4 acc[4][4];
#pragma unroll
  for (int i = 0; i < 4; i++)
#pragma unroll
    for (int j = 0; j < 4; j++) acc[i][j] = f32x4{0.f, 0.f, 0.f, 0.f};

  const us16* bbase = Btp + (long)z * 512 * 1024 + (long)n0 * KTOT;
  const long aSlice = (long)8192 * 512;

  for (int k0 = 0; k0 < KTOT; k0 += 64) {
    __syncthreads();
#pragma unroll
    for (int i = 0; i < 4; i++) {
      const int c = i * 256 + tid;
      const int r = c >> 3;
      const int col = ((c & 7) ^ (r & 7)) << 3;
      const int kg = k0 + col;
      const us16* a = (kg < 512) ? Ap    + (long)z * aSlice + (long)(m0 + r) * 512 + kg
                                 : other + (long)z * aSlice + (long)(m0 + r) * 512 + (kg - 512);
      gload16(a, &lA[c * 8]);
    }
#pragma unroll
    for (int i = 0; i < 4; i++) {
      const int c = i * 256 + tid;
      const int r = c >> 3;
      const int col = ((c & 7) ^ (r & 7)) << 3;
      gload16(bbase + (long)r * KTOT + (k0 + col), &lB[c * 8]);
    }
    __syncthreads();

#pragma unroll
    for (int ks = 0; ks < 2; ks++) {
      bf16x8 af[4], bfg[4];
      const int kc = ks * 32 + fk;
#pragma unroll
      for (int f = 0; f < 4; f++)
        af[f]  = *(const bf16x8*)&lA[(wm + f * 16 + fr) * 64 + (kc ^ xorkey)];
#pragma unroll
      for (int f = 0; f < 4; f++)
        bfg[f] = *(const bf16x8*)&lB[(wn + f * 16 + fr) * 64 + (kc ^ xorkey)];
#pragma unroll
      for (int fm = 0; fm < 4; fm++)
#pragma unroll
        for (int fn = 0; fn < 4; fn++)
          acc[fm][fn] = __builtin_amdgcn_mfma_f32_16x16x32_bf16(af[fm], bfg[fn], acc[fm][fn], 0, 0, 0);
    }
  }

  const float* bsl = bias + (long)z * 512;
  const float* wsl = dotW + (long)z * 512;
#pragma unroll
  for (int fm = 0; fm < 4; fm++) {
#pragma unroll
    for (int j = 0; j < 4; j++) {
      float p = 0.f;
#pragma unroll
      for (int fn = 0; fn < 4; fn++) {
        int col = n0 + wn + fn * 16 + fr;
        float v = acc[fm][fn][j] + bsl[col];
        v = lrelu(v);
        p += v * wsl[col];
      }
      p += __shfl_xor(p, 1); p += __shfl_xor(p, 2); p += __shfl_xor(p, 4); p += __shfl_xor(p, 8);
      if (fr == 0) {
        long row = (long)half * 65536 + (long)z * 8192 + (m0 + wm + fm * 16 + rbase + j);
        partial[row * 8 + blockIdx.y * 2 + (wv & 1)] = p;
      }
    }
  }
}

// ---------------------------------------------------------------------------
// Attention core + Tier B and Tier A2 wrappers.
// ---------------------------------------------------------------------------
DEVI void attn_core(const us16* __restrict__ src, us16* __restrict__ other,
                    int e, long b, int lane, us16* tbuf)
{
#pragma unroll
  for (int i = 0; i < 6; i++) {
    int c = i * 64 + lane;
    int r = c / 48, cc = c - r * 48;
    *(int4*)&tbuf[r * 392 + cc * 8] = *(const int4*)&src[c * 8];
  }
  __syncthreads();
  const int i = lane >> 3, j = lane & 7;
  const us16* selp = &tbuf[i * 392 + 128];
  const us16* keyp = &tbuf[j * 392];
  float acc = 0.f;
#pragma unroll
  for (int d = 0; d < 128; d += 8) {
    u16x8 s8 = *(const u16x8*)&selp[d];
    u16x8 k8 = *(const u16x8*)&keyp[d];
#pragma unroll
    for (int q = 0; q < 8; q++) acc += bf2f(s8[q]) * bf2f(k8[q]);
  }
  acc *= 0.088388347648318447f;
  float mx = acc;
  mx = fmaxf(mx, __shfl_xor(mx, 1)); mx = fmaxf(mx, __shfl_xor(mx, 2)); mx = fmaxf(mx, __shfl_xor(mx, 4));
  float ex = __expf(acc - mx);
  float sm = ex;
  sm += __shfl_xor(sm, 1); sm += __shfl_xor(sm, 2); sm += __shfl_xor(sm, 4);
  float wsm = ex / sm;
  float wj[8];
  const int ibase = lane & 56;
#pragma unroll
  for (int jj = 0; jj < 8; jj++) wj[jj] = __shfl(wsm, ibase + jj);
  const int dbase = (lane & 7) * 16;
  float o[16];
#pragma unroll
  for (int q = 0; q < 16; q++) o[q] = 0.f;
#pragma unroll
  for (int jj = 0; jj < 8; jj++) {
    u16x8 v0 = *(const u16x8*)&tbuf[jj * 392 + 256 + dbase];
    u16x8 v1 = *(const u16x8*)&tbuf[jj * 392 + 256 + dbase + 8];
    float wgt = wj[jj];
#pragma unroll
    for (int q = 0; q < 8; q++) { o[q] += wgt * bf2f(v0[q]); o[8 + q] += wgt * bf2f(v1[q]); }
  }
  u16x8 r0, r1;
#pragma unroll
  for (int q = 0; q < 8; q++) { r0[q] = f2bf(o[q]); r1[q] = f2bf(o[8 + q]); }
  us16* dst = other + ((long)i * 8192 + b) * 512 + e * 128 + dbase;
  *(u16x8*)&dst[0] = r0;
  *(u16x8*)&dst[8] = r1;
}

__global__ __launch_bounds__(256, 4)
void attn_k(const us16* __restrict__ ksv, us16* __restrict__ other, int e)
{
  __shared__ us16 t[4][8 * 392];
  const int wv = threadIdx.x >> 6, lane = threadIdx.x & 63;
  const long b = (long)blockIdx.x * 4 + wv;
  attn_core(ksv + b * 3072, other, e, b, lane, &t[wv][0]);
}

// Tier A2: grid (2048, 2); ebase passed from host (0 or 2).
__global__ __launch_bounds__(256, 4)
void attn2_k(const us16* __restrict__ ksv2, us16* __restrict__ other, int ebase)
{
  __shared__ us16 t[4][8 * 392];
  const int wv = threadIdx.x >> 6, lane = threadIdx.x & 63;
  const long b = (long)blockIdx.x * 4 + wv;
  const int el = blockIdx.y;
  attn_core(ksv2 + b * 6144 + el * 3072, other, ebase + el, b, lane, &t[wv][0]);
}

// merged final reduce: r < 65536 -> q (bc2), else v (bv2). grid 512 x 256.
__global__ void reduce2_k(const float* __restrict__ part, const float* __restrict__ b2c,
                          const float* __restrict__ b2v, float* __restrict__ out)
{
  int r = blockIdx.x * 256 + threadIdx.x;   // 0..131071
  const float4* p = (const float4*)(part + (long)r * 8);
  float4 a = p[0], b = p[1];
  float s = ((a.x + a.y) + (a.z + a.w)) + ((b.x + b.y) + (b.z + b.w));
  int agent = (r >> 13) & 7;
  out[r] = s + ((r < 65536) ? b2c[agent] : b2v[agent]);
}

// ---------------------------------------------------------------------------
extern "C" void kernel_launch(void* const* d_in, const int* in_sizes, int n_in,
                              void* d_out, int out_size, void* d_ws, size_t ws_size,
                              hipStream_t stream)
{
  const float* states = (const float*)d_in[0];
  const float* actions= (const float*)d_in[1];
  const float* Ws  = (const float*)d_in[2];
  const float* bs  = (const float*)d_in[3];
  const float* Wsa = (const float*)d_in[4];
  const float* bsa = (const float*)d_in[5];
  const float* Wk  = (const float*)d_in[6];
  const float* Wsel= (const float*)d_in[7];
  const float* Wv  = (const float*)d_in[8];
  const float* bv  = (const float*)d_in[9];
  const float* Wc1 = (const float*)d_in[10];
  const float* bc1 = (const float*)d_in[11];
  const float* Wc2 = (const float*)d_in[12];
  const float* bc2 = (const float*)d_in[13];
  const float* Wv1 = (const float*)d_in[14];
  const float* bv1 = (const float*)d_in[15];
  const float* Wv2 = (const float*)d_in[16];
  const float* bv2 = (const float*)d_in[17];

  char* ws = (char*)d_ws;
  constexpr size_t OFF_WST   = 0;
  constexpr size_t OFF_WSAT  = OFF_WST   + (size_t)8 * 512 * 64 * 2;
  constexpr size_t OFF_WKVST = OFF_WSAT  + (size_t)8 * 512 * 96 * 2;
  constexpr size_t OFF_WC1T  = OFF_WKVST + (size_t)4 * 384 * 512 * 2;
  constexpr size_t OFF_WV1T  = OFF_WC1T  + (size_t)8 * 512 * 1024 * 2;
  constexpr size_t OFF_ENC   = OFF_WV1T  + (size_t)8 * 512 * 1024 * 2;
  constexpr size_t OFF_OTHER = OFF_ENC   + (size_t)8 * 8192 * 512 * 2;
  constexpr size_t OFF_KSV   = OFF_OTHER + (size_t)8 * 8192 * 512 * 2;
  // Tier B: KSV (one head, 50.3 MB) + PART
  constexpr size_t OFF_PARTB = OFF_KSV   + (size_t)8192 * 8 * 384 * 2;
  constexpr size_t NEED_B    = OFF_PARTB + (size_t)131072 * 8 * 4;
  // Tier A2: KSV2 (two heads, 100.7 MB); PART + ENC2 aliased inside KSV2
  // region (only used after the last attn2 has consumed KSV2).
  constexpr size_t KSV2_BYTES = (size_t)8192 * 2 * 8 * 384 * 2;   // 100,663,296
  constexpr size_t NEED_A2    = OFF_KSV + KSV2_BYTES;             // ~254.5 MB
  constexpr size_t OFF_PARTA  = OFF_KSV;                          // 4 MB
  constexpr size_t OFF_ENC2   = OFF_KSV + (size_t)131072 * 8 * 4; // 67 MB
  if (ws_size < NEED_B) return;
  const bool bigws = (ws_size >= NEED_A2);

  us16* WST   = (us16*)(ws + OFF_WST);
  us16* WSAT  = (us16*)(ws + OFF_WSAT);
  us16* WKVST = (us16*)(ws + OFF_WKVST);
  us16* WC1T  = (us16*)(ws + OFF_WC1T);
  us16* WV1T  = (us16*)(ws + OFF_WV1T);
  us16* ENC   = (us16*)(ws + OFF_ENC);
  us16* OTHER = (us16*)(ws + OFF_OTHER);
  us16* KSV   = (us16*)(ws + OFF_KSV);      // tier B: one head; tier A2: two heads
  float* PARTB= (float*)(ws + OFF_PARTB);
  float* PARTA= (float*)(ws + OFF_PARTA);
  us16* ENC2  = (us16*)(ws + OFF_ENC2);

  dim3 tb(32, 8);
  tconvSA_k<<<dim3(3, 16, 16), tb, 0, stream>>>(Ws, Wsa, WST, WSAT);
  tconv3_k <<<dim3(16, 4, 12), tb, 0, stream>>>(Wk, Wsel, Wv, WKVST);
  tconvC_k <<<dim3(32, 16, 16),tb, 0, stream>>>(Wc1, Wv1, WC1T, WV1T);

  // sa_enc = lrelu([states|actions] @ Wsa + bsa)  -> ENC (bf16)
  enc_gemm_k<ASRC_F32_CAT, 96><<<dim3(64, 4, 8), 256, 0, stream>>>(
      states, (long)8192 * 64, actions, (long)8192 * 16, WSAT, (long)512 * 96, bsa, 512,
      ENC, (long)8192 * 512, 512);

  if (bigws) {
    // heads in pairs: ksv2 (3072 blocks = 3 exact rounds) + attn2
    for (int h = 0; h < 2; h++) {
      ksv2_k<<<dim3(64, 6, 8), 256, 0, stream>>>(
          ENC, WKVST + (size_t)(h * 2) * 384 * 512, bv + h * 256, KSV);
      attn2_k<<<dim3(2048, 2), 256, 0, stream>>>(KSV, OTHER, h * 2);
    }
    // s_enc -> ENC2 (aliased in the now-dead KSV2 region; stream-serial)
    enc_gemm_k<ASRC_F32, 64><<<dim3(64, 4, 8), 256, 0, stream>>>(
        states, (long)8192 * 64, nullptr, 0, WST, (long)512 * 64, bs, 512,
        ENC2, (long)8192 * 512, 512);
    // both MLP heads in one dispatch (4096 blocks = 4 exact rounds)
    dot2_k<<<dim3(64, 4, 16), 256, 0, stream>>>(
        ENC, ENC2, OTHER, WC1T, WV1T, bc1, bv1, Wc2, Wv2, PARTA);
    reduce2_k<<<dim3(512), 256, 0, stream>>>(PARTA, bc2, bv2, (float*)d_out);
  } else {
    for (int e = 0; e < 4; e++) {
      gemm64_k<false, EPI_KSV, 512><<<dim3(64, 3, 8), 256, 0, stream>>>(
          ENC, (long)8192 * 512, nullptr, 0, WKVST + (size_t)e * 384 * 512, 0, bv + e * 128,
          KSV, 384, 3072, nullptr, nullptr);
      attn_k<<<dim3(2048), 256, 0, stream>>>(KSV, OTHER, e);
    }
    gemm64_k<true, EPI_DOT, 1024><<<dim3(64, 4, 8), 256, 0, stream>>>(
        ENC, (long)8192 * 512, OTHER, (long)8192 * 512, WC1T, (long)512 * 1024, bc1,
        nullptr, 0, 0, Wc2, PARTB);
    enc_gemm_k<ASRC_F32, 64><<<dim3(64, 4, 8), 256, 0, stream>>>(
        states, (long)8192 * 64, nullptr, 0, WST, (long)512 * 64, bs, 512,
        ENC, (long)8192 * 512, 512);
    gemm64_k<true, EPI_DOT, 1024><<<dim3(64, 4, 8), 256, 0, stream>>>(
        ENC, (long)8192 * 512, OTHER, (long)8192 * 512, WV1T, (long)512 * 1024, bv1,
        nullptr, 0, 0, Wv2, PARTB + (size_t)65536 * 8);
    reduce2_k<<<dim3(512), 256, 0, stream>>>(PARTB, bc2, bv2, (float*)d_out);
  }
}